// Round 6
// baseline (5699.348 us; speedup 1.0000x reference)
//
#include <hip/hip_runtime.h>
#include <hip/hip_cooperative_groups.h>

namespace cg = cooperative_groups;

#define GN 64
#define N_TOTAL (GN * GN * GN)   // 262144
#define KOFF 24

typedef float f4 __attribute__((ext_vector_type(4)));

// 24 Manhattan-radius-2 offsets, sorted by linear delta (dx*4096 + dy*64 + dz)
// ascending. List is symmetric under negation: inv(k) = 23 - k.
__device__ constexpr int DLc[KOFF] = {
    -8192, -4160, -4097, -4096, -4095, -4032,
     -128,   -65,   -64,   -63,    -2,    -1,
        1,     2,    63,    64,    65,   128,
     4032,  4095,  4096,  4097,  4160,  8192};
__device__ constexpr int DXc[KOFF] = {
    -2, -1, -1, -1, -1, -1, 0, 0, 0, 0, 0, 0,
     0,  0,  0,  0,  0,  0, 1, 1, 1, 1, 1, 2};
__device__ constexpr int DYc[KOFF] = {
     0, -1,  0,  0,  0,  1, -2, -1, -1, -1, 0, 0,
     0,  0,  1,  1,  1,  2, -1,  0,  0,  0, 1, 0};
__device__ constexpr int DZc[KOFF] = {
     0,  0, -1,  0,  1,  0,  0, -1,  0,  1, -2, -1,
     1,  2, -1,  0,  1,  0,  0, -1,  0,  1,  0,  0};

// Deterministic re-pack of ev into INCOMING plane-major layout:
//   wIn[k*N + j] = weight of edge (j+DL[k] -> j)   (0 if that edge invalid).
__global__ __launch_bounds__(256) void pack_w_kernel(
    const float* __restrict__ ev, float* __restrict__ w) {
    int j = blockIdx.x * 256 + threadIdx.x;
    int z = j & 63, y = (j >> 6) & 63, x = j >> 12;

    int S = 0;
#pragma unroll
    for (int k = 0; k < KOFF; k++) {
        int dx = DXc[k], dy = DYc[k], dz = DZc[k];
        int x0 = max(0, -dx), x1 = min(64, 64 - dx);
        int y0 = max(0, -dy), y1 = min(64, 64 - dy);
        int z0 = max(0, -dz), z1 = min(64, 64 - dz);
        int ny = y1 - y0, nz = z1 - z0;
        int nxb = max(0, min(x, x1) - x0);
        int cnt = nxb * ny * nz;
        if (x >= x0 && x < x1) {
            cnt += max(0, min(y, y1) - y0) * nz;
            if (y >= y0 && y < y1)
                cnt += max(0, min(z, z1) - z0);
        }
        S += cnt;
    }

    int idx = 0;
#pragma unroll
    for (int k = 0; k < KOFF; k++) {
        int nx = x + DXc[k], ny = y + DYc[k], nz = z + DZc[k];
        bool ok = ((unsigned)nx < 64u) & ((unsigned)ny < 64u) &
                  ((unsigned)nz < 64u);
        if (ok) {
            w[(23 - k) * N_TOTAL + (j + DLc[k])] = ev[S + idx];
            idx++;
        } else {
            w[k * N_TOTAL + j] = 0.0f;
        }
    }
}

// ------------------ persistent cooperative path ------------------
// One thread per neuron, all T steps. w (24 incoming weights), v, out_{t-1},
// out_{t-2} live in VGPRs -> w never touches memory after the initial load.
// 256 blocks x 1024 threads = 1 block/CU (weakest co-residency requirement).
// __threadfence() before grid.sync() for cross-XCD visibility of the out
// ping-pong stores.
__global__ __launch_bounds__(1024, 4) void sim_kernel(
    const float* __restrict__ xext,
    const float* __restrict__ wpk,
    float* __restrict__ pb0,
    float* __restrict__ pb1,
    float* __restrict__ spk,
    int T) {
#pragma clang fp contract(off)
    cg::grid_group grid = cg::this_grid();
    int j = blockIdx.x * 1024 + threadIdx.x;
    int z = j & 63, y = (j >> 6) & 63, x = j >> 12;

    unsigned okm = 0;
#pragma unroll
    for (int k = 0; k < KOFF; k++) {
        int nx = x + DXc[k], ny = y + DYc[k], nz = z + DZc[k];
        bool ok = ((unsigned)nx < 64u) & ((unsigned)ny < 64u) &
                  ((unsigned)nz < 64u);
        okm |= (unsigned)ok << k;
    }

    float w[KOFF];
#pragma unroll
    for (int k = 0; k < KOFF; k++) w[k] = wpk[k * N_TOTAL + j];

    const float decay = expf(-1.0f / 20.0f);
    float vmem = -65.0f;
    float o1 = 0.0f;   // out_{t-1}[j]
    float o2 = 0.0f;   // out_{t-2}[j]

    for (int t = 0; t < T; t++) {
        const float* pb = (t & 1) ? pb0 : pb1;   // buf[(t-1)&1]
        float*       pw = (t & 1) ? pb1 : pb0;   // buf[t&1]

        float syn = 0.0f;
        if (t >= 2) {
#pragma unroll
            for (int k = 0; k < KOFF; k++) {
                bool ok = (okm >> k) & 1u;
                float p = 0.0f;
                if (ok) p = pb[j + DLc[k]];
                float a = (0.01f * o2) * p;
                float b = (0.005f * o2) * (1.0f - p);
                float c = 1e-5f * w[k];
                float dw = (a - b) - c;
                float cl = fminf(fmaxf(w[k] + dw, 0.0f), 1.0f);
                w[k] = ok ? cl : 0.0f;
                float m = w[k] * p;   // contract(off): mul then add
                syn = syn + m;        // k-ascending == segment_sum order
            }
        } else if (t == 1) {
#pragma unroll
            for (int k = 0; k < KOFF; k++) {
                bool ok = (okm >> k) & 1u;
                float p = 0.0f;
                if (ok) p = pb[j + DLc[k]];
                float m = w[k] * p;
                syn = syn + m;
            }
        }
        // t == 0: prev == 0 -> syn stays 0, no buffer read (poisoned ws ok).

        float I = syn + __builtin_nontemporal_load(xext + (size_t)t * N_TOTAL + j);
        float vn = (vmem * decay) + (I * (1.0f - decay));
        float spike = (vn >= -50.0f) ? 1.0f : 0.0f;
        float inhib = (vn <= -70.0f) ? 1.0f : 0.0f;
        float sg = 1.0f / (1.0f + expf(-((vn - (-60.0f)) * 0.5f)));
        float o = spike + ((1.0f - spike) * (1.0f - inhib)) * sg;
        vmem = (vn * (1.0f - spike)) + (spike * (-65.0f));
        pw[j] = o;
        __builtin_nontemporal_store(spike, spk + (size_t)t * N_TOTAL + j);
        o2 = o1;
        o1 = o;

        __threadfence();   // device-scope: publish pw across XCD L2s
        grid.sync();
    }
}

// ------------------ per-step fallback path (validated round-3) ------------------
template <int MODE>
__global__ __launch_bounds__(256) void step_kernel(
    const float* __restrict__ xext,
    const float* __restrict__ w_old,
    float* __restrict__ w_new,
    const float* __restrict__ prev,
    const float* __restrict__ prev2,
    float* __restrict__ out,
    float* __restrict__ v,
    float* __restrict__ spk) {
#pragma clang fp contract(off)
    int j0 = (blockIdx.x * 256 + threadIdx.x) * 4;
    int z0 = j0 & 63, y = (j0 >> 6) & 63, x = j0 >> 12;

    float syn[4] = {0.0f, 0.0f, 0.0f, 0.0f};
    float pre2[4];
    if (MODE == 2) {
        f4 q = *(const f4*)(prev2 + j0);
        pre2[0] = q.x; pre2[1] = q.y; pre2[2] = q.z; pre2[3] = q.w;
    }

    if (MODE >= 1) {
#pragma unroll
        for (int k = 0; k < KOFF; k++) {
            int nx = x + DXc[k], nyy = y + DYc[k];
            bool okxy = ((unsigned)nx < 64u) & ((unsigned)nyy < 64u);
            int nzb = z0 + DZc[k];
            f4 wq = *(const f4*)(w_old + k * N_TOTAL + j0);
            float wv[4] = {wq.x, wq.y, wq.z, wq.w};
            float nw[4];
#pragma unroll
            for (int i = 0; i < 4; i++) {
                bool ok = okxy & ((unsigned)(nzb + i) < 64u);
                float p = ok ? prev[j0 + i + DLc[k]] : 0.0f;
                float nwi;
                if (MODE == 2) {
                    float a = (0.01f * pre2[i]) * p;
                    float b = (0.005f * pre2[i]) * (1.0f - p);
                    float c = 1e-5f * wv[i];
                    float dw = (a - b) - c;
                    float cl = fminf(fmaxf(wv[i] + dw, 0.0f), 1.0f);
                    nwi = ok ? cl : 0.0f;
                } else {
                    nwi = wv[i];
                }
                nw[i] = nwi;
                float m = nwi * p;
                syn[i] = syn[i] + m;
            }
            if (MODE == 2) {
                f4 s; s.x = nw[0]; s.y = nw[1]; s.z = nw[2]; s.w = nw[3];
                *(f4*)(w_new + k * N_TOTAL + j0) = s;
            }
        }
    }

    const float decay = expf(-1.0f / 20.0f);
    f4 xq;
    xq.x = __builtin_nontemporal_load(xext + j0 + 0);
    xq.y = __builtin_nontemporal_load(xext + j0 + 1);
    xq.z = __builtin_nontemporal_load(xext + j0 + 2);
    xq.w = __builtin_nontemporal_load(xext + j0 + 3);
    f4 vq;
    if (MODE >= 1) vq = *(const f4*)(v + j0);

    f4 vo, oo, so;
    float xv[4] = {xq.x, xq.y, xq.z, xq.w};
    float vv[4] = {vq.x, vq.y, vq.z, vq.w};
    float vr[4], orr[4], sr[4];
#pragma unroll
    for (int i = 0; i < 4; i++) {
        float myv = (MODE == 0) ? -65.0f : vv[i];
        float I = syn[i] + xv[i];
        float vn = (myv * decay) + (I * (1.0f - decay));
        float spike = (vn >= -50.0f) ? 1.0f : 0.0f;
        float inhib = (vn <= -70.0f) ? 1.0f : 0.0f;
        float sg = 1.0f / (1.0f + expf(-((vn - (-60.0f)) * 0.5f)));
        float o = spike + ((1.0f - spike) * (1.0f - inhib)) * sg;
        vr[i] = (vn * (1.0f - spike)) + (spike * (-65.0f));
        orr[i] = o;
        sr[i] = spike;
    }
    vo.x = vr[0]; vo.y = vr[1]; vo.z = vr[2]; vo.w = vr[3];
    oo.x = orr[0]; oo.y = orr[1]; oo.z = orr[2]; oo.w = orr[3];
    so.x = sr[0]; so.y = sr[1]; so.z = sr[2]; so.w = sr[3];
    *(f4*)(v + j0) = vo;
    *(f4*)(out + j0) = oo;
    __builtin_nontemporal_store(so, (f4*)(spk + j0));
}

extern "C" void kernel_launch(void* const* d_in, const int* in_sizes, int n_in,
                              void* d_out, int out_size, void* d_ws, size_t ws_size,
                              hipStream_t stream) {
    const float* xext = (const float*)d_in[0];
    const float* ev   = (const float*)d_in[1];
    float* spk = (float*)d_out;

    int T = in_sizes[0] / N_TOTAL;   // 50

    // Workspace: W0 (24N) | W1 (24N) | P0 | P1 | P2 | v  -> 52*N ≈ 54.5 MB.
    // Coop path uses W0 as wpk and P0/P1 as the out ping-pong.
    float* W0 = (float*)d_ws;
    float* W1 = W0 + (size_t)N_TOTAL * KOFF;
    float* P0 = W1 + (size_t)N_TOTAL * KOFF;
    float* P1 = P0 + N_TOTAL;
    float* P2 = P1 + N_TOTAL;
    float* vb = P2 + N_TOTAL;

    pack_w_kernel<<<N_TOTAL / 256, 256, 0, stream>>>(ev, W0);

    const float* wpk = W0;
    void* args[] = {(void*)&xext, (void*)&wpk, (void*)&P0, (void*)&P1,
                    (void*)&spk, (void*)&T};
    hipError_t cerr = hipLaunchCooperativeKernel((const void*)sim_kernel,
                                                 dim3(N_TOTAL / 1024),
                                                 dim3(1024), args, 0, stream);
    if (cerr == hipSuccess) return;
    (void)hipGetLastError();  // clear the failed-launch error state

    // Fallback: validated per-step path.
    float* P[3] = {P0, P1, P2};
    const int NB = N_TOTAL / 4 / 256;
    for (int t = 0; t < T; t++) {
        float* po  = P[t % 3];
        float* pr  = P[(t + 2) % 3];
        float* pr2 = P[(t + 1) % 3];
        const float* xt = xext + (size_t)t * N_TOTAL;
        float* st = spk + (size_t)t * N_TOTAL;
        if (t == 0) {
            step_kernel<0><<<NB, 256, 0, stream>>>(xt, W0, W1, pr, pr2, po, vb, st);
        } else if (t == 1) {
            step_kernel<1><<<NB, 256, 0, stream>>>(xt, W0, W1, pr, pr2, po, vb, st);
        } else {
            float* wo = (t & 1) ? W0 : W1;
            float* wn = (t & 1) ? W1 : W0;
            step_kernel<2><<<NB, 256, 0, stream>>>(xt, wo, wn, pr, pr2, po, vb, st);
        }
    }
}

// Round 7
// 616.145 us; speedup vs baseline: 9.2500x; 9.2500x over previous
//
#include <hip/hip_runtime.h>

#define GN 64
#define N_TOTAL (GN * GN * GN)   // 262144
#define KOFF 24

typedef float f4 __attribute__((ext_vector_type(4)));

// 24 Manhattan-radius-2 offsets, sorted by linear delta (dx*4096 + dy*64 + dz)
// ascending. List is symmetric under negation: inv(k) = 23 - k.
__device__ constexpr int DLc[KOFF] = {
    -8192, -4160, -4097, -4096, -4095, -4032,
     -128,   -65,   -64,   -63,    -2,    -1,
        1,     2,    63,    64,    65,   128,
     4032,  4095,  4096,  4097,  4160,  8192};
__device__ constexpr int DXc[KOFF] = {
    -2, -1, -1, -1, -1, -1, 0, 0, 0, 0, 0, 0,
     0,  0,  0,  0,  0,  0, 1, 1, 1, 1, 1, 2};
__device__ constexpr int DYc[KOFF] = {
     0, -1,  0,  0,  0,  1, -2, -1, -1, -1, 0, 0,
     0,  0,  1,  1,  1,  2, -1,  0,  0,  0, 1, 0};
__device__ constexpr int DZc[KOFF] = {
     0,  0, -1,  0,  1,  0,  0, -1,  0,  1, -2, -1,
     1,  2, -1,  0,  1,  0,  0, -1,  0,  1,  0,  0};

// Deterministic re-pack of ev into INCOMING plane-major layout:
//   wIn[k*N + j] = weight of edge (j+DL[k] -> j)   (0 if that edge invalid).
__global__ __launch_bounds__(256) void pack_w_kernel(
    const float* __restrict__ ev, float* __restrict__ w) {
    int j = blockIdx.x * 256 + threadIdx.x;
    int z = j & 63, y = (j >> 6) & 63, x = j >> 12;

    int S = 0;
#pragma unroll
    for (int k = 0; k < KOFF; k++) {
        int dx = DXc[k], dy = DYc[k], dz = DZc[k];
        int x0 = max(0, -dx), x1 = min(64, 64 - dx);
        int y0 = max(0, -dy), y1 = min(64, 64 - dy);
        int z0 = max(0, -dz), z1 = min(64, 64 - dz);
        int ny = y1 - y0, nz = z1 - z0;
        int nxb = max(0, min(x, x1) - x0);
        int cnt = nxb * ny * nz;
        if (x >= x0 && x < x1) {
            cnt += max(0, min(y, y1) - y0) * nz;
            if (y >= y0 && y < y1)
                cnt += max(0, min(z, z1) - z0);
        }
        S += cnt;
    }

    int idx = 0;
#pragma unroll
    for (int k = 0; k < KOFF; k++) {
        int nx = x + DXc[k], ny = y + DYc[k], nz = z + DZc[k];
        bool ok = ((unsigned)nx < 64u) & ((unsigned)ny < 64u) &
                  ((unsigned)nz < 64u);
        if (ok) {
            w[(23 - k) * N_TOTAL + (j + DLc[k])] = ev[S + idx];
            idx++;
        } else {
            w[k * N_TOTAL + j] = 0.0f;
        }
    }
}

// ------------------ persistent cooperative path ------------------
// One thread per neuron, all T steps; w/v/out-history in VGPRs.
// Cross-XCD coherence WITHOUT cache flushes: the out ping-pong uses
// agent-scope relaxed atomic loads/stores (sc1 -> coherent point, bypassing
// the non-coherent per-XCD L2s). Barrier: __syncthreads() (compiler drains
// vmcnt(0) before s_barrier, so all sc1 stores have reached the coherent
// point) -> leader atomicAdd -> leader spins on monotonic target -> sync.
__global__ __launch_bounds__(1024, 1) void sim_kernel(
    const float* __restrict__ xext,
    const float* __restrict__ wpk,
    float* __restrict__ pb0,
    float* __restrict__ pb1,
    float* __restrict__ spk,
    unsigned* __restrict__ ctr,
    int T) {
#pragma clang fp contract(off)
    int j = blockIdx.x * 1024 + threadIdx.x;
    int z = j & 63, y = (j >> 6) & 63, x = j >> 12;

    unsigned okm = 0;
#pragma unroll
    for (int k = 0; k < KOFF; k++) {
        int nx = x + DXc[k], ny = y + DYc[k], nz = z + DZc[k];
        bool ok = ((unsigned)nx < 64u) & ((unsigned)ny < 64u) &
                  ((unsigned)nz < 64u);
        okm |= (unsigned)ok << k;
    }

    float w[KOFF];
#pragma unroll
    for (int k = 0; k < KOFF; k++) w[k] = wpk[k * N_TOTAL + j];

    const float decay = expf(-1.0f / 20.0f);
    float vmem = -65.0f;
    float o1 = 0.0f;   // out_{t-1}[j]
    float o2 = 0.0f;   // out_{t-2}[j]

    for (int t = 0; t < T; t++) {
        float* pb = (t & 1) ? pb0 : pb1;   // buf[(t-1)&1]
        float* pw = (t & 1) ? pb1 : pb0;   // buf[t&1]

        float syn = 0.0f;
        if (t >= 2) {
#pragma unroll
            for (int k = 0; k < KOFF; k++) {
                bool ok = (okm >> k) & 1u;
                float p = 0.0f;
                if (ok)
                    p = __hip_atomic_load(pb + j + DLc[k], __ATOMIC_RELAXED,
                                          __HIP_MEMORY_SCOPE_AGENT);
                float a = (0.01f * o2) * p;
                float b = (0.005f * o2) * (1.0f - p);
                float c = 1e-5f * w[k];
                float dw = (a - b) - c;
                float cl = fminf(fmaxf(w[k] + dw, 0.0f), 1.0f);
                w[k] = ok ? cl : 0.0f;
                float m = w[k] * p;   // contract(off): mul then add
                syn = syn + m;        // k-ascending == segment_sum order
            }
        } else if (t == 1) {
#pragma unroll
            for (int k = 0; k < KOFF; k++) {
                bool ok = (okm >> k) & 1u;
                float p = 0.0f;
                if (ok)
                    p = __hip_atomic_load(pb + j + DLc[k], __ATOMIC_RELAXED,
                                          __HIP_MEMORY_SCOPE_AGENT);
                float m = w[k] * p;
                syn = syn + m;
            }
        }
        // t == 0: prev == 0 -> syn stays 0, no buffer read (poisoned ws ok).

        float I = syn + __builtin_nontemporal_load(xext + (size_t)t * N_TOTAL + j);
        float vn = (vmem * decay) + (I * (1.0f - decay));
        float spike = (vn >= -50.0f) ? 1.0f : 0.0f;
        float inhib = (vn <= -70.0f) ? 1.0f : 0.0f;
        float sg = 1.0f / (1.0f + expf(-((vn - (-60.0f)) * 0.5f)));
        float o = spike + ((1.0f - spike) * (1.0f - inhib)) * sg;
        vmem = (vn * (1.0f - spike)) + (spike * (-65.0f));
        __hip_atomic_store(pw + j, o, __ATOMIC_RELAXED,
                           __HIP_MEMORY_SCOPE_AGENT);
        __builtin_nontemporal_store(spike, spk + (size_t)t * N_TOTAL + j);
        o2 = o1;
        o1 = o;

        // ---- lightweight grid barrier (no cache maintenance) ----
        __syncthreads();   // drains vmcnt(0): sc1 stores are at coherent point
        if (threadIdx.x == 0) {
            __hip_atomic_fetch_add(ctr, 1u, __ATOMIC_RELAXED,
                                   __HIP_MEMORY_SCOPE_AGENT);
            unsigned tgt = (unsigned)gridDim.x * (unsigned)(t + 1);
            while (__hip_atomic_load(ctr, __ATOMIC_RELAXED,
                                     __HIP_MEMORY_SCOPE_AGENT) < tgt)
                __builtin_amdgcn_s_sleep(2);
        }
        __syncthreads();
    }
}

// ------------------ per-step fallback path (validated round-3) ------------------
template <int MODE>
__global__ __launch_bounds__(256) void step_kernel(
    const float* __restrict__ xext,
    const float* __restrict__ w_old,
    float* __restrict__ w_new,
    const float* __restrict__ prev,
    const float* __restrict__ prev2,
    float* __restrict__ out,
    float* __restrict__ v,
    float* __restrict__ spk) {
#pragma clang fp contract(off)
    int j0 = (blockIdx.x * 256 + threadIdx.x) * 4;
    int z0 = j0 & 63, y = (j0 >> 6) & 63, x = j0 >> 12;

    float syn[4] = {0.0f, 0.0f, 0.0f, 0.0f};
    float pre2[4];
    if (MODE == 2) {
        f4 q = *(const f4*)(prev2 + j0);
        pre2[0] = q.x; pre2[1] = q.y; pre2[2] = q.z; pre2[3] = q.w;
    }

    if (MODE >= 1) {
#pragma unroll
        for (int k = 0; k < KOFF; k++) {
            int nx = x + DXc[k], nyy = y + DYc[k];
            bool okxy = ((unsigned)nx < 64u) & ((unsigned)nyy < 64u);
            int nzb = z0 + DZc[k];
            f4 wq = *(const f4*)(w_old + k * N_TOTAL + j0);
            float wv[4] = {wq.x, wq.y, wq.z, wq.w};
            float nw[4];
#pragma unroll
            for (int i = 0; i < 4; i++) {
                bool ok = okxy & ((unsigned)(nzb + i) < 64u);
                float p = ok ? prev[j0 + i + DLc[k]] : 0.0f;
                float nwi;
                if (MODE == 2) {
                    float a = (0.01f * pre2[i]) * p;
                    float b = (0.005f * pre2[i]) * (1.0f - p);
                    float c = 1e-5f * wv[i];
                    float dw = (a - b) - c;
                    float cl = fminf(fmaxf(wv[i] + dw, 0.0f), 1.0f);
                    nwi = ok ? cl : 0.0f;
                } else {
                    nwi = wv[i];
                }
                nw[i] = nwi;
                float m = nwi * p;
                syn[i] = syn[i] + m;
            }
            if (MODE == 2) {
                f4 s; s.x = nw[0]; s.y = nw[1]; s.z = nw[2]; s.w = nw[3];
                *(f4*)(w_new + k * N_TOTAL + j0) = s;
            }
        }
    }

    const float decay = expf(-1.0f / 20.0f);
    f4 xq;
    xq.x = __builtin_nontemporal_load(xext + j0 + 0);
    xq.y = __builtin_nontemporal_load(xext + j0 + 1);
    xq.z = __builtin_nontemporal_load(xext + j0 + 2);
    xq.w = __builtin_nontemporal_load(xext + j0 + 3);
    f4 vq;
    if (MODE >= 1) vq = *(const f4*)(v + j0);

    f4 vo, oo, so;
    float xv[4] = {xq.x, xq.y, xq.z, xq.w};
    float vv[4] = {vq.x, vq.y, vq.z, vq.w};
    float vr[4], orr[4], sr[4];
#pragma unroll
    for (int i = 0; i < 4; i++) {
        float myv = (MODE == 0) ? -65.0f : vv[i];
        float I = syn[i] + xv[i];
        float vn = (myv * decay) + (I * (1.0f - decay));
        float spike = (vn >= -50.0f) ? 1.0f : 0.0f;
        float inhib = (vn <= -70.0f) ? 1.0f : 0.0f;
        float sg = 1.0f / (1.0f + expf(-((vn - (-60.0f)) * 0.5f)));
        float o = spike + ((1.0f - spike) * (1.0f - inhib)) * sg;
        vr[i] = (vn * (1.0f - spike)) + (spike * (-65.0f));
        orr[i] = o;
        sr[i] = spike;
    }
    vo.x = vr[0]; vo.y = vr[1]; vo.z = vr[2]; vo.w = vr[3];
    oo.x = orr[0]; oo.y = orr[1]; oo.z = orr[2]; oo.w = orr[3];
    so.x = sr[0]; so.y = sr[1]; so.z = sr[2]; so.w = sr[3];
    *(f4*)(v + j0) = vo;
    *(f4*)(out + j0) = oo;
    __builtin_nontemporal_store(so, (f4*)(spk + j0));
}

extern "C" void kernel_launch(void* const* d_in, const int* in_sizes, int n_in,
                              void* d_out, int out_size, void* d_ws, size_t ws_size,
                              hipStream_t stream) {
    const float* xext = (const float*)d_in[0];
    const float* ev   = (const float*)d_in[1];
    float* spk = (float*)d_out;

    int T = in_sizes[0] / N_TOTAL;   // 50

    // Workspace: W0 (24N) | W1 (24N) | P0 | P1 | P2 | v | ctr  ≈ 54.5 MB.
    // Coop path uses W0 as wpk and P0/P1 as the out ping-pong.
    float* W0 = (float*)d_ws;
    float* W1 = W0 + (size_t)N_TOTAL * KOFF;
    float* P0 = W1 + (size_t)N_TOTAL * KOFF;
    float* P1 = P0 + N_TOTAL;
    float* P2 = P1 + N_TOTAL;
    float* vb = P2 + N_TOTAL;
    unsigned* ctr = (unsigned*)(vb + N_TOTAL);

    hipMemsetAsync(ctr, 0, sizeof(unsigned), stream);
    pack_w_kernel<<<N_TOTAL / 256, 256, 0, stream>>>(ev, W0);

    const float* wpk = W0;
    void* args[] = {(void*)&xext, (void*)&wpk, (void*)&P0, (void*)&P1,
                    (void*)&spk, (void*)&ctr, (void*)&T};
    hipError_t cerr = hipLaunchCooperativeKernel((const void*)sim_kernel,
                                                 dim3(N_TOTAL / 1024),
                                                 dim3(1024), args, 0, stream);
    if (cerr == hipSuccess) return;
    (void)hipGetLastError();  // clear the failed-launch error state

    // Fallback: validated per-step path.
    float* P[3] = {P0, P1, P2};
    const int NB = N_TOTAL / 4 / 256;
    for (int t = 0; t < T; t++) {
        float* po  = P[t % 3];
        float* pr  = P[(t + 2) % 3];
        float* pr2 = P[(t + 1) % 3];
        const float* xt = xext + (size_t)t * N_TOTAL;
        float* st = spk + (size_t)t * N_TOTAL;
        if (t == 0) {
            step_kernel<0><<<NB, 256, 0, stream>>>(xt, W0, W1, pr, pr2, po, vb, st);
        } else if (t == 1) {
            step_kernel<1><<<NB, 256, 0, stream>>>(xt, W0, W1, pr, pr2, po, vb, st);
        } else {
            float* wo = (t & 1) ? W0 : W1;
            float* wn = (t & 1) ? W1 : W0;
            step_kernel<2><<<NB, 256, 0, stream>>>(xt, wo, wn, pr, pr2, po, vb, st);
        }
    }
}

// Round 8
// 530.638 us; speedup vs baseline: 10.7405x; 1.1611x over previous
//
#include <hip/hip_runtime.h>

#define GN 64
#define N_TOTAL (GN * GN * GN)   // 262144
#define KOFF 24

typedef float f4 __attribute__((ext_vector_type(4)));

// 24 Manhattan-radius-2 offsets, sorted by linear delta (dx*4096 + dy*64 + dz)
// ascending. List is symmetric under negation: inv(k) = 23 - k.
__device__ constexpr int DLc[KOFF] = {
    -8192, -4160, -4097, -4096, -4095, -4032,
     -128,   -65,   -64,   -63,    -2,    -1,
        1,     2,    63,    64,    65,   128,
     4032,  4095,  4096,  4097,  4160,  8192};
__device__ constexpr int DXc[KOFF] = {
    -2, -1, -1, -1, -1, -1, 0, 0, 0, 0, 0, 0,
     0,  0,  0,  0,  0,  0, 1, 1, 1, 1, 1, 2};
__device__ constexpr int DYc[KOFF] = {
     0, -1,  0,  0,  0,  1, -2, -1, -1, -1, 0, 0,
     0,  0,  1,  1,  1,  2, -1,  0,  0,  0, 1, 0};
__device__ constexpr int DZc[KOFF] = {
     0,  0, -1,  0,  1,  0,  0, -1,  0,  1, -2, -1,
     1,  2, -1,  0,  1,  0,  0, -1,  0,  1,  0,  0};

// 12 distinct (dx,dy) != (0,0) groups; a wave = one z-row, so the dz variants
// of a group are lane-shifts of the group's dz=0 element.
#define NGRP 12
__device__ constexpr int GDXc[NGRP] = {-2, -1, -1, -1,  0,  0, 0, 0,  1, 1, 1, 2};
__device__ constexpr int GDYc[NGRP] = { 0, -1,  0,  1, -2, -1, 1, 2, -1, 0, 1, 0};
__device__ constexpr int GDLc[NGRP] = {-8192, -4160, -4096, -4032, -128, -64,
                                        64, 128, 4032, 4096, 4160, 8192};
// group id per k (-1 = pure-z group, served from own o1)
__device__ constexpr int GIDc[KOFF] = {
    0, 1, 2, 2, 2, 3, 4, 5, 5, 5, -1, -1,
    -1, -1, 6, 6, 6, 7, 8, 9, 9, 9, 10, 11};

// Deterministic re-pack of ev into INCOMING plane-major layout:
//   wIn[k*N + j] = weight of edge (j+DL[k] -> j)   (0 if that edge invalid).
__global__ __launch_bounds__(256) void pack_w_kernel(
    const float* __restrict__ ev, float* __restrict__ w) {
    int j = blockIdx.x * 256 + threadIdx.x;
    int z = j & 63, y = (j >> 6) & 63, x = j >> 12;

    int S = 0;
#pragma unroll
    for (int k = 0; k < KOFF; k++) {
        int dx = DXc[k], dy = DYc[k], dz = DZc[k];
        int x0 = max(0, -dx), x1 = min(64, 64 - dx);
        int y0 = max(0, -dy), y1 = min(64, 64 - dy);
        int z0 = max(0, -dz), z1 = min(64, 64 - dz);
        int ny = y1 - y0, nz = z1 - z0;
        int nxb = max(0, min(x, x1) - x0);
        int cnt = nxb * ny * nz;
        if (x >= x0 && x < x1) {
            cnt += max(0, min(y, y1) - y0) * nz;
            if (y >= y0 && y < y1)
                cnt += max(0, min(z, z1) - z0);
        }
        S += cnt;
    }

    int idx = 0;
#pragma unroll
    for (int k = 0; k < KOFF; k++) {
        int nx = x + DXc[k], ny = y + DYc[k], nz = z + DZc[k];
        bool ok = ((unsigned)nx < 64u) & ((unsigned)ny < 64u) &
                  ((unsigned)nz < 64u);
        if (ok) {
            w[(23 - k) * N_TOTAL + (j + DLc[k])] = ev[S + idx];
            idx++;
        } else {
            w[k * N_TOTAL + j] = 0.0f;
        }
    }
}

// ------------------ persistent cooperative path ------------------
// One thread per neuron, all T steps; w/v/out-history in VGPRs.
// Cross-XCD coherence: agent-scope relaxed (sc1) atomics on the out
// ping-pong, no cache maintenance. 12 group loads + 12 shuffles replace the
// 24-way gather (wave = one z-row). xext prefetched before the barrier so
// its HBM latency overlaps arrival.
__global__ __launch_bounds__(1024, 1) void sim_kernel(
    const float* __restrict__ xext,
    const float* __restrict__ wpk,
    float* __restrict__ pb0,
    float* __restrict__ pb1,
    float* __restrict__ spk,
    unsigned* __restrict__ ctr,
    int T) {
#pragma clang fp contract(off)
    int j = blockIdx.x * 1024 + threadIdx.x;
    int z = j & 63, y = (j >> 6) & 63, x = j >> 12;
    int lane = threadIdx.x & 63;   // == z

    unsigned okm = 0;
#pragma unroll
    for (int k = 0; k < KOFF; k++) {
        int nx = x + DXc[k], ny = y + DYc[k], nz = z + DZc[k];
        bool ok = ((unsigned)nx < 64u) & ((unsigned)ny < 64u) &
                  ((unsigned)nz < 64u);
        okm |= (unsigned)ok << k;
    }

    float w[KOFF];
#pragma unroll
    for (int k = 0; k < KOFF; k++) w[k] = wpk[k * N_TOTAL + j];

    const float decay = expf(-1.0f / 20.0f);
    float vmem = -65.0f;
    float o1 = 0.0f;   // out_{t-1}[j]
    float o2 = 0.0f;   // out_{t-2}[j]
    float xv = __builtin_nontemporal_load(xext + j);   // slice t=0

    for (int t = 0; t < T; t++) {
        float* pb = (t & 1) ? pb0 : pb1;   // buf[(t-1)&1]
        float* pw = (t & 1) ? pb1 : pb0;   // buf[t&1]

        float syn = 0.0f;
        if (t >= 1) {
            // group loads: validity is wave-uniform (one (x,y) per wave) ->
            // scalar branch; boundary waves skip the load entirely.
            float r[NGRP];
#pragma unroll
            for (int g = 0; g < NGRP; g++) {
                int nx = x + GDXc[g], ny = y + GDYc[g];
                bool gok = ((unsigned)nx < 64u) & ((unsigned)ny < 64u);
                float rv = 0.0f;
                if (gok)
                    rv = __hip_atomic_load(pb + j + GDLc[g], __ATOMIC_RELAXED,
                                           __HIP_MEMORY_SCOPE_AGENT);
                r[g] = rv;
            }
            if (t >= 2) {
#pragma unroll
                for (int k = 0; k < KOFF; k++) {
                    int g = GIDc[k], dz = DZc[k];
                    float src = (g < 0) ? o1 : r[g];
                    float p = (dz == 0) ? src : __shfl(src, lane + dz, 64);
                    p = ((okm >> k) & 1u) ? p : 0.0f;
                    float a = (0.01f * o2) * p;
                    float b = (0.005f * o2) * (1.0f - p);
                    float c = 1e-5f * w[k];
                    float dw = (a - b) - c;
                    float cl = fminf(fmaxf(w[k] + dw, 0.0f), 1.0f);
                    w[k] = ((okm >> k) & 1u) ? cl : 0.0f;
                    float m = w[k] * p;   // contract(off): mul then add
                    syn = syn + m;        // k-ascending == segment_sum order
                }
            } else {   // t == 1: syn with stored w, no plasticity yet
#pragma unroll
                for (int k = 0; k < KOFF; k++) {
                    int g = GIDc[k], dz = DZc[k];
                    float src = (g < 0) ? o1 : r[g];
                    float p = (dz == 0) ? src : __shfl(src, lane + dz, 64);
                    p = ((okm >> k) & 1u) ? p : 0.0f;
                    float m = w[k] * p;
                    syn = syn + m;
                }
            }
        }
        // t == 0: prev == 0 -> syn stays 0, no buffer read (poisoned ws ok).

        float I = syn + xv;
        float vn = (vmem * decay) + (I * (1.0f - decay));
        float spike = (vn >= -50.0f) ? 1.0f : 0.0f;
        float inhib = (vn <= -70.0f) ? 1.0f : 0.0f;
        float sg = 1.0f / (1.0f + expf(-((vn - (-60.0f)) * 0.5f)));
        float o = spike + ((1.0f - spike) * (1.0f - inhib)) * sg;
        vmem = (vn * (1.0f - spike)) + (spike * (-65.0f));
        __hip_atomic_store(pw + j, o, __ATOMIC_RELAXED,
                           __HIP_MEMORY_SCOPE_AGENT);
        __builtin_nontemporal_store(spike, spk + (size_t)t * N_TOTAL + j);
        o2 = o1;
        o1 = o;

        // prefetch next step's external input; its latency overlaps the
        // barrier (vmcnt drain happens while other blocks arrive).
        int tn = (t + 1 < T) ? (t + 1) : t;
        float xnext = __builtin_nontemporal_load(xext + (size_t)tn * N_TOTAL + j);

        // ---- lightweight grid barrier (no cache maintenance) ----
        __syncthreads();   // drains vmcnt: sc1 stores are at coherent point
        if (threadIdx.x == 0) {
            __hip_atomic_fetch_add(ctr, 1u, __ATOMIC_RELAXED,
                                   __HIP_MEMORY_SCOPE_AGENT);
            unsigned tgt = (unsigned)gridDim.x * (unsigned)(t + 1);
            while (__hip_atomic_load(ctr, __ATOMIC_RELAXED,
                                     __HIP_MEMORY_SCOPE_AGENT) < tgt)
                __builtin_amdgcn_s_sleep(1);
        }
        __syncthreads();
        xv = xnext;
    }
}

// ------------------ per-step fallback path (validated round-3) ------------------
template <int MODE>
__global__ __launch_bounds__(256) void step_kernel(
    const float* __restrict__ xext,
    const float* __restrict__ w_old,
    float* __restrict__ w_new,
    const float* __restrict__ prev,
    const float* __restrict__ prev2,
    float* __restrict__ out,
    float* __restrict__ v,
    float* __restrict__ spk) {
#pragma clang fp contract(off)
    int j0 = (blockIdx.x * 256 + threadIdx.x) * 4;
    int z0 = j0 & 63, y = (j0 >> 6) & 63, x = j0 >> 12;

    float syn[4] = {0.0f, 0.0f, 0.0f, 0.0f};
    float pre2[4];
    if (MODE == 2) {
        f4 q = *(const f4*)(prev2 + j0);
        pre2[0] = q.x; pre2[1] = q.y; pre2[2] = q.z; pre2[3] = q.w;
    }

    if (MODE >= 1) {
#pragma unroll
        for (int k = 0; k < KOFF; k++) {
            int nx = x + DXc[k], nyy = y + DYc[k];
            bool okxy = ((unsigned)nx < 64u) & ((unsigned)nyy < 64u);
            int nzb = z0 + DZc[k];
            f4 wq = *(const f4*)(w_old + k * N_TOTAL + j0);
            float wv[4] = {wq.x, wq.y, wq.z, wq.w};
            float nw[4];
#pragma unroll
            for (int i = 0; i < 4; i++) {
                bool ok = okxy & ((unsigned)(nzb + i) < 64u);
                float p = ok ? prev[j0 + i + DLc[k]] : 0.0f;
                float nwi;
                if (MODE == 2) {
                    float a = (0.01f * pre2[i]) * p;
                    float b = (0.005f * pre2[i]) * (1.0f - p);
                    float c = 1e-5f * wv[i];
                    float dw = (a - b) - c;
                    float cl = fminf(fmaxf(wv[i] + dw, 0.0f), 1.0f);
                    nwi = ok ? cl : 0.0f;
                } else {
                    nwi = wv[i];
                }
                nw[i] = nwi;
                float m = nwi * p;
                syn[i] = syn[i] + m;
            }
            if (MODE == 2) {
                f4 s; s.x = nw[0]; s.y = nw[1]; s.z = nw[2]; s.w = nw[3];
                *(f4*)(w_new + k * N_TOTAL + j0) = s;
            }
        }
    }

    const float decay = expf(-1.0f / 20.0f);
    f4 xq;
    xq.x = __builtin_nontemporal_load(xext + j0 + 0);
    xq.y = __builtin_nontemporal_load(xext + j0 + 1);
    xq.z = __builtin_nontemporal_load(xext + j0 + 2);
    xq.w = __builtin_nontemporal_load(xext + j0 + 3);
    f4 vq;
    if (MODE >= 1) vq = *(const f4*)(v + j0);

    f4 vo, oo, so;
    float xv[4] = {xq.x, xq.y, xq.z, xq.w};
    float vv[4] = {vq.x, vq.y, vq.z, vq.w};
    float vr[4], orr[4], sr[4];
#pragma unroll
    for (int i = 0; i < 4; i++) {
        float myv = (MODE == 0) ? -65.0f : vv[i];
        float I = syn[i] + xv[i];
        float vn = (myv * decay) + (I * (1.0f - decay));
        float spike = (vn >= -50.0f) ? 1.0f : 0.0f;
        float inhib = (vn <= -70.0f) ? 1.0f : 0.0f;
        float sg = 1.0f / (1.0f + expf(-((vn - (-60.0f)) * 0.5f)));
        float o = spike + ((1.0f - spike) * (1.0f - inhib)) * sg;
        vr[i] = (vn * (1.0f - spike)) + (spike * (-65.0f));
        orr[i] = o;
        sr[i] = spike;
    }
    vo.x = vr[0]; vo.y = vr[1]; vo.z = vr[2]; vo.w = vr[3];
    oo.x = orr[0]; oo.y = orr[1]; oo.z = orr[2]; oo.w = orr[3];
    so.x = sr[0]; so.y = sr[1]; so.z = sr[2]; so.w = sr[3];
    *(f4*)(v + j0) = vo;
    *(f4*)(out + j0) = oo;
    __builtin_nontemporal_store(so, (f4*)(spk + j0));
}

extern "C" void kernel_launch(void* const* d_in, const int* in_sizes, int n_in,
                              void* d_out, int out_size, void* d_ws, size_t ws_size,
                              hipStream_t stream) {
    const float* xext = (const float*)d_in[0];
    const float* ev   = (const float*)d_in[1];
    float* spk = (float*)d_out;

    int T = in_sizes[0] / N_TOTAL;   // 50

    // Workspace: W0 (24N) | W1 (24N) | P0 | P1 | P2 | v | ctr  ≈ 54.5 MB.
    float* W0 = (float*)d_ws;
    float* W1 = W0 + (size_t)N_TOTAL * KOFF;
    float* P0 = W1 + (size_t)N_TOTAL * KOFF;
    float* P1 = P0 + N_TOTAL;
    float* P2 = P1 + N_TOTAL;
    float* vb = P2 + N_TOTAL;
    unsigned* ctr = (unsigned*)(vb + N_TOTAL);

    hipMemsetAsync(ctr, 0, sizeof(unsigned), stream);
    pack_w_kernel<<<N_TOTAL / 256, 256, 0, stream>>>(ev, W0);

    const float* wpk = W0;
    void* args[] = {(void*)&xext, (void*)&wpk, (void*)&P0, (void*)&P1,
                    (void*)&spk, (void*)&ctr, (void*)&T};
    hipError_t cerr = hipLaunchCooperativeKernel((const void*)sim_kernel,
                                                 dim3(N_TOTAL / 1024),
                                                 dim3(1024), args, 0, stream);
    if (cerr == hipSuccess) return;
    (void)hipGetLastError();  // clear the failed-launch error state

    // Fallback: validated per-step path.
    float* P[3] = {P0, P1, P2};
    const int NB = N_TOTAL / 4 / 256;
    for (int t = 0; t < T; t++) {
        float* po  = P[t % 3];
        float* pr  = P[(t + 2) % 3];
        float* pr2 = P[(t + 1) % 3];
        const float* xt = xext + (size_t)t * N_TOTAL;
        float* st = spk + (size_t)t * N_TOTAL;
        if (t == 0) {
            step_kernel<0><<<NB, 256, 0, stream>>>(xt, W0, W1, pr, pr2, po, vb, st);
        } else if (t == 1) {
            step_kernel<1><<<NB, 256, 0, stream>>>(xt, W0, W1, pr, pr2, po, vb, st);
        } else {
            float* wo = (t & 1) ? W0 : W1;
            float* wn = (t & 1) ? W1 : W0;
            step_kernel<2><<<NB, 256, 0, stream>>>(xt, wo, wn, pr, pr2, po, vb, st);
        }
    }
}

// Round 10
// 527.973 us; speedup vs baseline: 10.7948x; 1.0050x over previous
//
#include <hip/hip_runtime.h>

#define GN 64
#define N_TOTAL (GN * GN * GN)   // 262144
#define KOFF 24

typedef float f4 __attribute__((ext_vector_type(4)));

// 24 Manhattan-radius-2 offsets, sorted by linear delta (dx*4096 + dy*64 + dz)
// ascending. List is symmetric under negation: inv(k) = 23 - k.
__device__ constexpr int DLc[KOFF] = {
    -8192, -4160, -4097, -4096, -4095, -4032,
     -128,   -65,   -64,   -63,    -2,    -1,
        1,     2,    63,    64,    65,   128,
     4032,  4095,  4096,  4097,  4160,  8192};
__device__ constexpr int DXc[KOFF] = {
    -2, -1, -1, -1, -1, -1, 0, 0, 0, 0, 0, 0,
     0,  0,  0,  0,  0,  0, 1, 1, 1, 1, 1, 2};
__device__ constexpr int DYc[KOFF] = {
     0, -1,  0,  0,  0,  1, -2, -1, -1, -1, 0, 0,
     0,  0,  1,  1,  1,  2, -1,  0,  0,  0, 1, 0};
__device__ constexpr int DZc[KOFF] = {
     0,  0, -1,  0,  1,  0,  0, -1,  0,  1, -2, -1,
     1,  2, -1,  0,  1,  0,  0, -1,  0,  1,  0,  0};

// 12 distinct (dx,dy) != (0,0) groups; a wave = one z-row, so the dz variants
// of a group are lane-shifts of the group's dz=0 element.
#define NGRP 12
__device__ constexpr int GDXc[NGRP] = {-2, -1, -1, -1,  0,  0, 0, 0,  1, 1, 1, 2};
__device__ constexpr int GDYc[NGRP] = { 0, -1,  0,  1, -2, -1, 1, 2, -1, 0, 1, 0};
__device__ constexpr int GDLc[NGRP] = {-8192, -4160, -4096, -4032, -128, -64,
                                        64, 128, 4032, 4096, 4160, 8192};
// group id per k (-1 = pure-z group, served from own o1)
__device__ constexpr int GIDc[KOFF] = {
    0, 1, 2, 2, 2, 3, 4, 5, 5, 5, -1, -1,
    -1, -1, 6, 6, 6, 7, 8, 9, 9, 9, 10, 11};

// Deterministic re-pack of ev into INCOMING plane-major layout:
//   wIn[k*N + j] = weight of edge (j+DL[k] -> j)   (0 if that edge invalid).
__global__ __launch_bounds__(256) void pack_w_kernel(
    const float* __restrict__ ev, float* __restrict__ w) {
    int j = blockIdx.x * 256 + threadIdx.x;
    int z = j & 63, y = (j >> 6) & 63, x = j >> 12;

    int S = 0;
#pragma unroll
    for (int k = 0; k < KOFF; k++) {
        int dx = DXc[k], dy = DYc[k], dz = DZc[k];
        int x0 = max(0, -dx), x1 = min(64, 64 - dx);
        int y0 = max(0, -dy), y1 = min(64, 64 - dy);
        int z0 = max(0, -dz), z1 = min(64, 64 - dz);
        int ny = y1 - y0, nz = z1 - z0;
        int nxb = max(0, min(x, x1) - x0);
        int cnt = nxb * ny * nz;
        if (x >= x0 && x < x1) {
            cnt += max(0, min(y, y1) - y0) * nz;
            if (y >= y0 && y < y1)
                cnt += max(0, min(z, z1) - z0);
        }
        S += cnt;
    }

    int idx = 0;
#pragma unroll
    for (int k = 0; k < KOFF; k++) {
        int nx = x + DXc[k], ny = y + DYc[k], nz = z + DZc[k];
        bool ok = ((unsigned)nx < 64u) & ((unsigned)ny < 64u) &
                  ((unsigned)nz < 64u);
        if (ok) {
            w[(23 - k) * N_TOTAL + (j + DLc[k])] = ev[S + idx];
            idx++;
        } else {
            w[k * N_TOTAL + j] = 0.0f;
        }
    }
}

// ------------------ persistent cooperative path ------------------
// One thread per neuron, all T steps; w/v/out-history in VGPRs.
// Cross-XCD coherence: agent-scope relaxed (sc1) atomics on the out
// ping-pong. GLOBAL barrier per step (validated ordering pattern from the
// passing round-8 kernel: vmcnt drain -> atomic RMW publish -> relaxed sc1
// observe -> __syncthreads), but with PARALLEL arrival/observation:
// publish = atomicAdd to own slot ctr[bid] (256 distinct addrs, no
// contention); wait = wave 0's 64 lanes each poll 4 slots until ALL 256
// slots >= t.
__global__ __launch_bounds__(1024, 1) void sim_kernel(
    const float* __restrict__ xext,
    const float* __restrict__ wpk,
    float* __restrict__ pb0,
    float* __restrict__ pb1,
    float* __restrict__ spk,
    unsigned* __restrict__ ctr,      // one counter per block (256)
    int T) {
#pragma clang fp contract(off)
    int j = blockIdx.x * 1024 + threadIdx.x;
    int z = j & 63, y = (j >> 6) & 63, x = j >> 12;
    int lane = threadIdx.x & 63;   // == z

    unsigned okm = 0;
#pragma unroll
    for (int k = 0; k < KOFF; k++) {
        int nx = x + DXc[k], ny = y + DYc[k], nz = z + DZc[k];
        bool ok = ((unsigned)nx < 64u) & ((unsigned)ny < 64u) &
                  ((unsigned)nz < 64u);
        okm |= (unsigned)ok << k;
    }

    float w[KOFF];
#pragma unroll
    for (int k = 0; k < KOFF; k++) w[k] = wpk[k * N_TOTAL + j];

    const float decay = expf(-1.0f / 20.0f);
    float vmem = -65.0f;
    float o1 = 0.0f;   // out_{t-1}[j]
    float o2 = 0.0f;   // out_{t-2}[j]
    float xv = __builtin_nontemporal_load(xext + j);   // slice t=0

    for (int t = 0; t < T; t++) {
        float* pb = (t & 1) ? pb0 : pb1;   // buf[(t-1)&1]
        float* pw = (t & 1) ? pb1 : pb0;   // buf[t&1]

        // ---- wait: ALL blocks published step t (completed t-1) ----
        if (t >= 1) {
            if ((int)threadIdx.x < 64) {
                const unsigned* cp = ctr + threadIdx.x * 4;
                for (;;) {
                    unsigned a = __hip_atomic_load(cp + 0, __ATOMIC_RELAXED,
                                                   __HIP_MEMORY_SCOPE_AGENT);
                    unsigned b = __hip_atomic_load(cp + 1, __ATOMIC_RELAXED,
                                                   __HIP_MEMORY_SCOPE_AGENT);
                    unsigned c = __hip_atomic_load(cp + 2, __ATOMIC_RELAXED,
                                                   __HIP_MEMORY_SCOPE_AGENT);
                    unsigned d = __hip_atomic_load(cp + 3, __ATOMIC_RELAXED,
                                                   __HIP_MEMORY_SCOPE_AGENT);
                    unsigned m = min(min(a, b), min(c, d));
                    if (m >= (unsigned)t) break;
                    __builtin_amdgcn_s_sleep(1);
                }
            }
            __syncthreads();
        }

        float syn = 0.0f;
        if (t >= 1) {
            // group loads: validity is wave-uniform (one (x,y) per wave) ->
            // scalar branch; boundary waves skip the load entirely.
            float r[NGRP];
#pragma unroll
            for (int g = 0; g < NGRP; g++) {
                int nx = x + GDXc[g], ny = y + GDYc[g];
                bool gok = ((unsigned)nx < 64u) & ((unsigned)ny < 64u);
                float rv = 0.0f;
                if (gok)
                    rv = __hip_atomic_load(pb + j + GDLc[g], __ATOMIC_RELAXED,
                                           __HIP_MEMORY_SCOPE_AGENT);
                r[g] = rv;
            }
            if (t >= 2) {
#pragma unroll
                for (int k = 0; k < KOFF; k++) {
                    int g = GIDc[k], dz = DZc[k];
                    float src = (g < 0) ? o1 : r[g];
                    float p = (dz == 0) ? src : __shfl(src, lane + dz, 64);
                    p = ((okm >> k) & 1u) ? p : 0.0f;
                    float a = (0.01f * o2) * p;
                    float b = (0.005f * o2) * (1.0f - p);
                    float c = 1e-5f * w[k];
                    float dw = (a - b) - c;
                    float cl = fminf(fmaxf(w[k] + dw, 0.0f), 1.0f);
                    w[k] = ((okm >> k) & 1u) ? cl : 0.0f;
                    float m = w[k] * p;   // contract(off): mul then add
                    syn = syn + m;        // k-ascending == segment_sum order
                }
            } else {   // t == 1: syn with stored w, no plasticity yet
#pragma unroll
                for (int k = 0; k < KOFF; k++) {
                    int g = GIDc[k], dz = DZc[k];
                    float src = (g < 0) ? o1 : r[g];
                    float p = (dz == 0) ? src : __shfl(src, lane + dz, 64);
                    p = ((okm >> k) & 1u) ? p : 0.0f;
                    float m = w[k] * p;
                    syn = syn + m;
                }
            }
        }
        // t == 0: prev == 0 -> syn stays 0, no buffer read (poisoned ws ok).

        float I = syn + xv;
        float vn = (vmem * decay) + (I * (1.0f - decay));
        float spike = (vn >= -50.0f) ? 1.0f : 0.0f;
        float inhib = (vn <= -70.0f) ? 1.0f : 0.0f;
        float sg = 1.0f / (1.0f + expf(-((vn - (-60.0f)) * 0.5f)));
        float o = spike + ((1.0f - spike) * (1.0f - inhib)) * sg;
        vmem = (vn * (1.0f - spike)) + (spike * (-65.0f));
        __hip_atomic_store(pw + j, o, __ATOMIC_RELAXED,
                           __HIP_MEMORY_SCOPE_AGENT);
        __builtin_nontemporal_store(spike, spk + (size_t)t * N_TOTAL + j);
        o2 = o1;
        o1 = o;

        // prefetch next step's external input (overlaps publish/wait)
        int tn = (t + 1 < T) ? (t + 1) : t;
        float xnext = __builtin_nontemporal_load(xext + (size_t)tn * N_TOTAL + j);

        // ---- publish: drain stores, then bump own slot (parallel RMW) ----
        __syncthreads();   // vmcnt(0) drain: sc1 stores at coherent point
        if (threadIdx.x == 0)
            __hip_atomic_fetch_add(ctr + blockIdx.x, 1u, __ATOMIC_RELAXED,
                                   __HIP_MEMORY_SCOPE_AGENT);
        xv = xnext;
    }
}

// ------------------ per-step fallback path (validated round-3) ------------------
template <int MODE>
__global__ __launch_bounds__(256) void step_kernel(
    const float* __restrict__ xext,
    const float* __restrict__ w_old,
    float* __restrict__ w_new,
    const float* __restrict__ prev,
    const float* __restrict__ prev2,
    float* __restrict__ out,
    float* __restrict__ v,
    float* __restrict__ spk) {
#pragma clang fp contract(off)
    int j0 = (blockIdx.x * 256 + threadIdx.x) * 4;
    int z0 = j0 & 63, y = (j0 >> 6) & 63, x = j0 >> 12;

    float syn[4] = {0.0f, 0.0f, 0.0f, 0.0f};
    float pre2[4];
    if (MODE == 2) {
        f4 q = *(const f4*)(prev2 + j0);
        pre2[0] = q.x; pre2[1] = q.y; pre2[2] = q.z; pre2[3] = q.w;
    }

    if (MODE >= 1) {
#pragma unroll
        for (int k = 0; k < KOFF; k++) {
            int nx = x + DXc[k], nyy = y + DYc[k];
            bool okxy = ((unsigned)nx < 64u) & ((unsigned)nyy < 64u);
            int nzb = z0 + DZc[k];
            f4 wq = *(const f4*)(w_old + k * N_TOTAL + j0);
            float wv[4] = {wq.x, wq.y, wq.z, wq.w};
            float nw[4];
#pragma unroll
            for (int i = 0; i < 4; i++) {
                bool ok = okxy & ((unsigned)(nzb + i) < 64u);
                float p = ok ? prev[j0 + i + DLc[k]] : 0.0f;
                float nwi;
                if (MODE == 2) {
                    float a = (0.01f * pre2[i]) * p;
                    float b = (0.005f * pre2[i]) * (1.0f - p);
                    float c = 1e-5f * wv[i];
                    float dw = (a - b) - c;
                    float cl = fminf(fmaxf(wv[i] + dw, 0.0f), 1.0f);
                    nwi = ok ? cl : 0.0f;
                } else {
                    nwi = wv[i];
                }
                nw[i] = nwi;
                float m = nwi * p;
                syn[i] = syn[i] + m;
            }
            if (MODE == 2) {
                f4 s; s.x = nw[0]; s.y = nw[1]; s.z = nw[2]; s.w = nw[3];
                *(f4*)(w_new + k * N_TOTAL + j0) = s;
            }
        }
    }

    const float decay = expf(-1.0f / 20.0f);
    f4 xq;
    xq.x = __builtin_nontemporal_load(xext + j0 + 0);
    xq.y = __builtin_nontemporal_load(xext + j0 + 1);
    xq.z = __builtin_nontemporal_load(xext + j0 + 2);
    xq.w = __builtin_nontemporal_load(xext + j0 + 3);
    f4 vq;
    if (MODE >= 1) vq = *(const f4*)(v + j0);

    f4 vo, oo, so;
    float xv[4] = {xq.x, xq.y, xq.z, xq.w};
    float vv[4] = {vq.x, vq.y, vq.z, vq.w};
    float vr[4], orr[4], sr[4];
#pragma unroll
    for (int i = 0; i < 4; i++) {
        float myv = (MODE == 0) ? -65.0f : vv[i];
        float I = syn[i] + xv[i];
        float vn = (myv * decay) + (I * (1.0f - decay));
        float spike = (vn >= -50.0f) ? 1.0f : 0.0f;
        float inhib = (vn <= -70.0f) ? 1.0f : 0.0f;
        float sg = 1.0f / (1.0f + expf(-((vn - (-60.0f)) * 0.5f)));
        float o = spike + ((1.0f - spike) * (1.0f - inhib)) * sg;
        vr[i] = (vn * (1.0f - spike)) + (spike * (-65.0f));
        orr[i] = o;
        sr[i] = spike;
    }
    vo.x = vr[0]; vo.y = vr[1]; vo.z = vr[2]; vo.w = vr[3];
    oo.x = orr[0]; oo.y = orr[1]; oo.z = orr[2]; oo.w = orr[3];
    so.x = sr[0]; so.y = sr[1]; so.z = sr[2]; so.w = sr[3];
    *(f4*)(v + j0) = vo;
    *(f4*)(out + j0) = oo;
    __builtin_nontemporal_store(so, (f4*)(spk + j0));
}

extern "C" void kernel_launch(void* const* d_in, const int* in_sizes, int n_in,
                              void* d_out, int out_size, void* d_ws, size_t ws_size,
                              hipStream_t stream) {
    const float* xext = (const float*)d_in[0];
    const float* ev   = (const float*)d_in[1];
    float* spk = (float*)d_out;

    int T = in_sizes[0] / N_TOTAL;   // 50

    // Workspace: W0 (24N) | W1 (24N) | P0 | P1 | P2 | v | ctr[256]  ≈ 54.5 MB.
    float* W0 = (float*)d_ws;
    float* W1 = W0 + (size_t)N_TOTAL * KOFF;
    float* P0 = W1 + (size_t)N_TOTAL * KOFF;
    float* P1 = P0 + N_TOTAL;
    float* P2 = P1 + N_TOTAL;
    float* vb = P2 + N_TOTAL;
    unsigned* ctr = (unsigned*)(vb + N_TOTAL);

    hipMemsetAsync(ctr, 0, 256 * sizeof(unsigned), stream);
    pack_w_kernel<<<N_TOTAL / 256, 256, 0, stream>>>(ev, W0);

    const float* wpk = W0;
    void* args[] = {(void*)&xext, (void*)&wpk, (void*)&P0, (void*)&P1,
                    (void*)&spk, (void*)&ctr, (void*)&T};
    hipError_t cerr = hipLaunchCooperativeKernel((const void*)sim_kernel,
                                                 dim3(N_TOTAL / 1024),
                                                 dim3(1024), args, 0, stream);
    if (cerr == hipSuccess) return;
    (void)hipGetLastError();  // clear the failed-launch error state

    // Fallback: validated per-step path.
    float* P[3] = {P0, P1, P2};
    const int NB = N_TOTAL / 4 / 256;
    for (int t = 0; t < T; t++) {
        float* po  = P[t % 3];
        float* pr  = P[(t + 2) % 3];
        float* pr2 = P[(t + 1) % 3];
        const float* xt = xext + (size_t)t * N_TOTAL;
        float* st = spk + (size_t)t * N_TOTAL;
        if (t == 0) {
            step_kernel<0><<<NB, 256, 0, stream>>>(xt, W0, W1, pr, pr2, po, vb, st);
        } else if (t == 1) {
            step_kernel<1><<<NB, 256, 0, stream>>>(xt, W0, W1, pr, pr2, po, vb, st);
        } else {
            float* wo = (t & 1) ? W0 : W1;
            float* wn = (t & 1) ? W1 : W0;
            step_kernel<2><<<NB, 256, 0, stream>>>(xt, wo, wn, pr, pr2, po, vb, st);
        }
    }
}

// Round 11
// 521.478 us; speedup vs baseline: 10.9292x; 1.0125x over previous
//
#include <hip/hip_runtime.h>

#define GN 64
#define N_TOTAL (GN * GN * GN)   // 262144
#define KOFF 24

typedef float f4 __attribute__((ext_vector_type(4)));

// 24 Manhattan-radius-2 offsets, sorted by linear delta (dx*4096 + dy*64 + dz)
// ascending. List is symmetric under negation: inv(k) = 23 - k.
__device__ constexpr int DLc[KOFF] = {
    -8192, -4160, -4097, -4096, -4095, -4032,
     -128,   -65,   -64,   -63,    -2,    -1,
        1,     2,    63,    64,    65,   128,
     4032,  4095,  4096,  4097,  4160,  8192};
__device__ constexpr int DXc[KOFF] = {
    -2, -1, -1, -1, -1, -1, 0, 0, 0, 0, 0, 0,
     0,  0,  0,  0,  0,  0, 1, 1, 1, 1, 1, 2};
__device__ constexpr int DYc[KOFF] = {
     0, -1,  0,  0,  0,  1, -2, -1, -1, -1, 0, 0,
     0,  0,  1,  1,  1,  2, -1,  0,  0,  0, 1, 0};
__device__ constexpr int DZc[KOFF] = {
     0,  0, -1,  0,  1,  0,  0, -1,  0,  1, -2, -1,
     1,  2, -1,  0,  1,  0,  0, -1,  0,  1,  0,  0};

// 12 distinct (dx,dy) != (0,0) groups; a wave = one z-row, so the dz variants
// of a group are lane-shifts of the group's dz=0 element.
#define NGRP 12
__device__ constexpr int GDXc[NGRP] = {-2, -1, -1, -1,  0,  0, 0, 0,  1, 1, 1, 2};
__device__ constexpr int GDYc[NGRP] = { 0, -1,  0,  1, -2, -1, 1, 2, -1, 0, 1, 0};
__device__ constexpr int GDLc[NGRP] = {-8192, -4160, -4096, -4032, -128, -64,
                                        64, 128, 4032, 4096, 4160, 8192};
// group id per k (-1 = pure-z group, served from own o1)
__device__ constexpr int GIDc[KOFF] = {
    0, 1, 2, 2, 2, 3, 4, 5, 5, 5, -1, -1,
    -1, -1, 6, 6, 6, 7, 8, 9, 9, 9, 10, 11};

// Closed-form edge-count prefix: number of edges whose row-linear-index < j,
// evaluated at unraveled coords (x,y,z) of j.  Works for j == N via (64,0,0).
__device__ __forceinline__ int edge_prefix(int x, int y, int z) {
    int S = 0;
#pragma unroll
    for (int k = 0; k < KOFF; k++) {
        int dx = DXc[k], dy = DYc[k], dz = DZc[k];
        int x0 = max(0, -dx), x1 = min(64, 64 - dx);
        int y0 = max(0, -dy), y1 = min(64, 64 - dy);
        int z0 = max(0, -dz), z1 = min(64, 64 - dz);
        int ny = y1 - y0, nz = z1 - z0;
        int nxb = max(0, min(x, x1) - x0);
        int cnt = nxb * ny * nz;
        if (x >= x0 && x < x1) {
            cnt += max(0, min(y, y1) - y0) * nz;
            if (y >= y0 && y < y1)
                cnt += max(0, min(z, z1) - z0);
        }
        S += cnt;
    }
    return S;
}

// Deterministic re-pack of ev into INCOMING plane-major layout:
//   wIn[k*N + j] = weight of edge (j+DL[k] -> j)   (0 if that edge invalid).
// ev reads staged through LDS: block's whole segment [S(j0), S(j0+256))
// (<= 6144 floats) loaded coalesced, then scattered per-thread from LDS
// (the direct form was a 64-way gather per k -> 46 us).  Also zeroes ctr.
__global__ __launch_bounds__(256) void pack_w_kernel(
    const float* __restrict__ ev, float* __restrict__ w,
    unsigned* __restrict__ ctr) {
    __shared__ float lds[6144];
    int tid = threadIdx.x;
    int j = blockIdx.x * 256 + tid;
    if (blockIdx.x == 0) ctr[tid] = 0;   // 256 progress counters
    int z = j & 63, y = (j >> 6) & 63, x = j >> 12;

    int j0 = blockIdx.x * 256, j1 = j0 + 256;
    int Sblk = edge_prefix(j0 >> 12, (j0 >> 6) & 63, 0);
    int Send = edge_prefix(j1 >> 12, (j1 >> 6) & 63, 0);
    int Sj   = edge_prefix(x, y, z);

    int len = Send - Sblk;
    for (int i = tid; i < len; i += 256)
        lds[i] = ev[Sblk + i];
    __syncthreads();

    int rel = Sj - Sblk;
#pragma unroll
    for (int k = 0; k < KOFF; k++) {
        int nx = x + DXc[k], ny = y + DYc[k], nz = z + DZc[k];
        bool ok = ((unsigned)nx < 64u) & ((unsigned)ny < 64u) &
                  ((unsigned)nz < 64u);
        if (ok) {
            w[(23 - k) * N_TOTAL + (j + DLc[k])] = lds[rel];
            rel++;
        } else {
            w[k * N_TOTAL + j] = 0.0f;
        }
    }
}

// ------------------ persistent cooperative path ------------------
// One thread per neuron, all T steps; w/v/out-history in VGPRs.
// Cross-XCD coherence: agent-scope relaxed (sc1) atomics on the out
// ping-pong. GLOBAL barrier per step, validated ordering (round 8/10):
// vmcnt drain -> atomicAdd RMW publish (own slot) -> relaxed sc1 observe of
// all 256 slots -> __syncthreads.  NEW: only the pw (data) store sits before
// the publish drain; the spk stream-out and next-step xext prefetch are
// issued AFTER the publish so their HBM latency overlaps the poll instead of
// gating the barrier (they only need to complete by the NEXT wait / kernel
// end, which drains them anyway).
__global__ __launch_bounds__(1024, 1) void sim_kernel(
    const float* __restrict__ xext,
    const float* __restrict__ wpk,
    float* __restrict__ pb0,
    float* __restrict__ pb1,
    float* __restrict__ spk,
    unsigned* __restrict__ ctr,      // one counter per block (256)
    int T) {
#pragma clang fp contract(off)
    int j = blockIdx.x * 1024 + threadIdx.x;
    int z = j & 63, y = (j >> 6) & 63, x = j >> 12;
    int lane = threadIdx.x & 63;   // == z

    unsigned okm = 0;
#pragma unroll
    for (int k = 0; k < KOFF; k++) {
        int nx = x + DXc[k], ny = y + DYc[k], nz = z + DZc[k];
        bool ok = ((unsigned)nx < 64u) & ((unsigned)ny < 64u) &
                  ((unsigned)nz < 64u);
        okm |= (unsigned)ok << k;
    }

    float w[KOFF];
#pragma unroll
    for (int k = 0; k < KOFF; k++) w[k] = wpk[k * N_TOTAL + j];

    const float decay = expf(-1.0f / 20.0f);
    float vmem = -65.0f;
    float o1 = 0.0f;   // out_{t-1}[j]
    float o2 = 0.0f;   // out_{t-2}[j]
    float xv = __builtin_nontemporal_load(xext + j);   // slice t=0

    for (int t = 0; t < T; t++) {
        float* pb = (t & 1) ? pb0 : pb1;   // buf[(t-1)&1]
        float* pw = (t & 1) ? pb1 : pb0;   // buf[t&1]

        // ---- wait: ALL blocks published step t (completed t-1) ----
        if (t >= 1) {
            if ((int)threadIdx.x < 64) {
                const unsigned* cp = ctr + threadIdx.x * 4;
                for (;;) {
                    unsigned a = __hip_atomic_load(cp + 0, __ATOMIC_RELAXED,
                                                   __HIP_MEMORY_SCOPE_AGENT);
                    unsigned b = __hip_atomic_load(cp + 1, __ATOMIC_RELAXED,
                                                   __HIP_MEMORY_SCOPE_AGENT);
                    unsigned c = __hip_atomic_load(cp + 2, __ATOMIC_RELAXED,
                                                   __HIP_MEMORY_SCOPE_AGENT);
                    unsigned d = __hip_atomic_load(cp + 3, __ATOMIC_RELAXED,
                                                   __HIP_MEMORY_SCOPE_AGENT);
                    unsigned m = min(min(a, b), min(c, d));
                    if (m >= (unsigned)t) break;
                    __builtin_amdgcn_s_sleep(1);
                }
            }
            __syncthreads();
        }

        float syn = 0.0f;
        if (t >= 1) {
            // group loads: validity is wave-uniform (one (x,y) per wave) ->
            // scalar branch; boundary waves skip the load entirely.
            float r[NGRP];
#pragma unroll
            for (int g = 0; g < NGRP; g++) {
                int nx = x + GDXc[g], ny = y + GDYc[g];
                bool gok = ((unsigned)nx < 64u) & ((unsigned)ny < 64u);
                float rv = 0.0f;
                if (gok)
                    rv = __hip_atomic_load(pb + j + GDLc[g], __ATOMIC_RELAXED,
                                           __HIP_MEMORY_SCOPE_AGENT);
                r[g] = rv;
            }
            if (t >= 2) {
#pragma unroll
                for (int k = 0; k < KOFF; k++) {
                    int g = GIDc[k], dz = DZc[k];
                    float src = (g < 0) ? o1 : r[g];
                    float p = (dz == 0) ? src : __shfl(src, lane + dz, 64);
                    p = ((okm >> k) & 1u) ? p : 0.0f;
                    float a = (0.01f * o2) * p;
                    float b = (0.005f * o2) * (1.0f - p);
                    float c = 1e-5f * w[k];
                    float dw = (a - b) - c;
                    float cl = fminf(fmaxf(w[k] + dw, 0.0f), 1.0f);
                    w[k] = ((okm >> k) & 1u) ? cl : 0.0f;
                    float m = w[k] * p;   // contract(off): mul then add
                    syn = syn + m;        // k-ascending == segment_sum order
                }
            } else {   // t == 1: syn with stored w, no plasticity yet
#pragma unroll
                for (int k = 0; k < KOFF; k++) {
                    int g = GIDc[k], dz = DZc[k];
                    float src = (g < 0) ? o1 : r[g];
                    float p = (dz == 0) ? src : __shfl(src, lane + dz, 64);
                    p = ((okm >> k) & 1u) ? p : 0.0f;
                    float m = w[k] * p;
                    syn = syn + m;
                }
            }
        }
        // t == 0: prev == 0 -> syn stays 0, no buffer read (poisoned ws ok).

        float I = syn + xv;
        float vn = (vmem * decay) + (I * (1.0f - decay));
        float spike = (vn >= -50.0f) ? 1.0f : 0.0f;
        float inhib = (vn <= -70.0f) ? 1.0f : 0.0f;
        float sg = 1.0f / (1.0f + expf(-((vn - (-60.0f)) * 0.5f)));
        float o = spike + ((1.0f - spike) * (1.0f - inhib)) * sg;
        vmem = (vn * (1.0f - spike)) + (spike * (-65.0f));
        __hip_atomic_store(pw + j, o, __ATOMIC_RELAXED,
                           __HIP_MEMORY_SCOPE_AGENT);
        o2 = o1;
        o1 = o;

        // ---- publish: drain data store, then bump own slot (parallel RMW) ----
        __syncthreads();   // vmcnt(0) drain: pw sc1 store at coherent point
        if (threadIdx.x == 0)
            __hip_atomic_fetch_add(ctr + blockIdx.x, 1u, __ATOMIC_RELAXED,
                                   __HIP_MEMORY_SCOPE_AGENT);

        // ---- post-publish streaming (latency hides under next wait) ----
        __builtin_nontemporal_store(spike, spk + (size_t)t * N_TOTAL + j);
        int tn = (t + 1 < T) ? (t + 1) : t;
        xv = __builtin_nontemporal_load(xext + (size_t)tn * N_TOTAL + j);
    }
}

// ------------------ per-step fallback path (validated round-3) ------------------
template <int MODE>
__global__ __launch_bounds__(256) void step_kernel(
    const float* __restrict__ xext,
    const float* __restrict__ w_old,
    float* __restrict__ w_new,
    const float* __restrict__ prev,
    const float* __restrict__ prev2,
    float* __restrict__ out,
    float* __restrict__ v,
    float* __restrict__ spk) {
#pragma clang fp contract(off)
    int j0 = (blockIdx.x * 256 + threadIdx.x) * 4;
    int z0 = j0 & 63, y = (j0 >> 6) & 63, x = j0 >> 12;

    float syn[4] = {0.0f, 0.0f, 0.0f, 0.0f};
    float pre2[4];
    if (MODE == 2) {
        f4 q = *(const f4*)(prev2 + j0);
        pre2[0] = q.x; pre2[1] = q.y; pre2[2] = q.z; pre2[3] = q.w;
    }

    if (MODE >= 1) {
#pragma unroll
        for (int k = 0; k < KOFF; k++) {
            int nx = x + DXc[k], nyy = y + DYc[k];
            bool okxy = ((unsigned)nx < 64u) & ((unsigned)nyy < 64u);
            int nzb = z0 + DZc[k];
            f4 wq = *(const f4*)(w_old + k * N_TOTAL + j0);
            float wv[4] = {wq.x, wq.y, wq.z, wq.w};
            float nw[4];
#pragma unroll
            for (int i = 0; i < 4; i++) {
                bool ok = okxy & ((unsigned)(nzb + i) < 64u);
                float p = ok ? prev[j0 + i + DLc[k]] : 0.0f;
                float nwi;
                if (MODE == 2) {
                    float a = (0.01f * pre2[i]) * p;
                    float b = (0.005f * pre2[i]) * (1.0f - p);
                    float c = 1e-5f * wv[i];
                    float dw = (a - b) - c;
                    float cl = fminf(fmaxf(wv[i] + dw, 0.0f), 1.0f);
                    nwi = ok ? cl : 0.0f;
                } else {
                    nwi = wv[i];
                }
                nw[i] = nwi;
                float m = nwi * p;
                syn[i] = syn[i] + m;
            }
            if (MODE == 2) {
                f4 s; s.x = nw[0]; s.y = nw[1]; s.z = nw[2]; s.w = nw[3];
                *(f4*)(w_new + k * N_TOTAL + j0) = s;
            }
        }
    }

    const float decay = expf(-1.0f / 20.0f);
    f4 xq;
    xq.x = __builtin_nontemporal_load(xext + j0 + 0);
    xq.y = __builtin_nontemporal_load(xext + j0 + 1);
    xq.z = __builtin_nontemporal_load(xext + j0 + 2);
    xq.w = __builtin_nontemporal_load(xext + j0 + 3);
    f4 vq;
    if (MODE >= 1) vq = *(const f4*)(v + j0);

    f4 vo, oo, so;
    float xv[4] = {xq.x, xq.y, xq.z, xq.w};
    float vv[4] = {vq.x, vq.y, vq.z, vq.w};
    float vr[4], orr[4], sr[4];
#pragma unroll
    for (int i = 0; i < 4; i++) {
        float myv = (MODE == 0) ? -65.0f : vv[i];
        float I = syn[i] + xv[i];
        float vn = (myv * decay) + (I * (1.0f - decay));
        float spike = (vn >= -50.0f) ? 1.0f : 0.0f;
        float inhib = (vn <= -70.0f) ? 1.0f : 0.0f;
        float sg = 1.0f / (1.0f + expf(-((vn - (-60.0f)) * 0.5f)));
        float o = spike + ((1.0f - spike) * (1.0f - inhib)) * sg;
        vr[i] = (vn * (1.0f - spike)) + (spike * (-65.0f));
        orr[i] = o;
        sr[i] = spike;
    }
    vo.x = vr[0]; vo.y = vr[1]; vo.z = vr[2]; vo.w = vr[3];
    oo.x = orr[0]; oo.y = orr[1]; oo.z = orr[2]; oo.w = orr[3];
    so.x = sr[0]; so.y = sr[1]; so.z = sr[2]; so.w = sr[3];
    *(f4*)(v + j0) = vo;
    *(f4*)(out + j0) = oo;
    __builtin_nontemporal_store(so, (f4*)(spk + j0));
}

extern "C" void kernel_launch(void* const* d_in, const int* in_sizes, int n_in,
                              void* d_out, int out_size, void* d_ws, size_t ws_size,
                              hipStream_t stream) {
    const float* xext = (const float*)d_in[0];
    const float* ev   = (const float*)d_in[1];
    float* spk = (float*)d_out;

    int T = in_sizes[0] / N_TOTAL;   // 50

    // Workspace: W0 (24N) | W1 (24N) | P0 | P1 | P2 | v | ctr[256]  ≈ 54.5 MB.
    float* W0 = (float*)d_ws;
    float* W1 = W0 + (size_t)N_TOTAL * KOFF;
    float* P0 = W1 + (size_t)N_TOTAL * KOFF;
    float* P1 = P0 + N_TOTAL;
    float* P2 = P1 + N_TOTAL;
    float* vb = P2 + N_TOTAL;
    unsigned* ctr = (unsigned*)(vb + N_TOTAL);

    pack_w_kernel<<<N_TOTAL / 256, 256, 0, stream>>>(ev, W0, ctr);

    const float* wpk = W0;
    void* args[] = {(void*)&xext, (void*)&wpk, (void*)&P0, (void*)&P1,
                    (void*)&spk, (void*)&ctr, (void*)&T};
    hipError_t cerr = hipLaunchCooperativeKernel((const void*)sim_kernel,
                                                 dim3(N_TOTAL / 1024),
                                                 dim3(1024), args, 0, stream);
    if (cerr == hipSuccess) return;
    (void)hipGetLastError();  // clear the failed-launch error state

    // Fallback: validated per-step path.
    float* P[3] = {P0, P1, P2};
    const int NB = N_TOTAL / 4 / 256;
    for (int t = 0; t < T; t++) {
        float* po  = P[t % 3];
        float* pr  = P[(t + 2) % 3];
        float* pr2 = P[(t + 1) % 3];
        const float* xt = xext + (size_t)t * N_TOTAL;
        float* st = spk + (size_t)t * N_TOTAL;
        if (t == 0) {
            step_kernel<0><<<NB, 256, 0, stream>>>(xt, W0, W1, pr, pr2, po, vb, st);
        } else if (t == 1) {
            step_kernel<1><<<NB, 256, 0, stream>>>(xt, W0, W1, pr, pr2, po, vb, st);
        } else {
            float* wo = (t & 1) ? W0 : W1;
            float* wn = (t & 1) ? W1 : W0;
            step_kernel<2><<<NB, 256, 0, stream>>>(xt, wo, wn, pr, pr2, po, vb, st);
        }
    }
}

// Round 12
// 515.429 us; speedup vs baseline: 11.0575x; 1.0117x over previous
//
#include <hip/hip_runtime.h>

#define GN 64
#define N_TOTAL (GN * GN * GN)   // 262144
#define KOFF 24

typedef float f4 __attribute__((ext_vector_type(4)));

// 24 Manhattan-radius-2 offsets, sorted by linear delta (dx*4096 + dy*64 + dz)
// ascending. List is symmetric under negation: inv(k) = 23 - k.
__device__ constexpr int DLc[KOFF] = {
    -8192, -4160, -4097, -4096, -4095, -4032,
     -128,   -65,   -64,   -63,    -2,    -1,
        1,     2,    63,    64,    65,   128,
     4032,  4095,  4096,  4097,  4160,  8192};
__device__ constexpr int DXc[KOFF] = {
    -2, -1, -1, -1, -1, -1, 0, 0, 0, 0, 0, 0,
     0,  0,  0,  0,  0,  0, 1, 1, 1, 1, 1, 2};
__device__ constexpr int DYc[KOFF] = {
     0, -1,  0,  0,  0,  1, -2, -1, -1, -1, 0, 0,
     0,  0,  1,  1,  1,  2, -1,  0,  0,  0, 1, 0};
__device__ constexpr int DZc[KOFF] = {
     0,  0, -1,  0,  1,  0,  0, -1,  0,  1, -2, -1,
     1,  2, -1,  0,  1,  0,  0, -1,  0,  1,  0,  0};

// 12 distinct (dx,dy) != (0,0) groups; a wave = one z-row, so the dz variants
// of a group are lane-shifts of the group's dz=0 element.
#define NGRP 12
__device__ constexpr int GDXc[NGRP] = {-2, -1, -1, -1,  0,  0, 0, 0,  1, 1, 1, 2};
__device__ constexpr int GDYc[NGRP] = { 0, -1,  0,  1, -2, -1, 1, 2, -1, 0, 1, 0};
__device__ constexpr int GDLc[NGRP] = {-8192, -4160, -4096, -4032, -128, -64,
                                        64, 128, 4032, 4096, 4160, 8192};
// group id per k (-1 = pure-z group, served from own o1)
__device__ constexpr int GIDc[KOFF] = {
    0, 1, 2, 2, 2, 3, 4, 5, 5, 5, -1, -1,
    -1, -1, 6, 6, 6, 7, 8, 9, 9, 9, 10, 11};

// Closed-form edge-count prefix: number of edges whose row-linear-index < j,
// evaluated at unraveled coords (x,y,z) of j.  Works for j == N via (64,0,0).
__device__ __forceinline__ int edge_prefix(int x, int y, int z) {
    int S = 0;
#pragma unroll
    for (int k = 0; k < KOFF; k++) {
        int dx = DXc[k], dy = DYc[k], dz = DZc[k];
        int x0 = max(0, -dx), x1 = min(64, 64 - dx);
        int y0 = max(0, -dy), y1 = min(64, 64 - dy);
        int z0 = max(0, -dz), z1 = min(64, 64 - dz);
        int ny = y1 - y0, nz = z1 - z0;
        int nxb = max(0, min(x, x1) - x0);
        int cnt = nxb * ny * nz;
        if (x >= x0 && x < x1) {
            cnt += max(0, min(y, y1) - y0) * nz;
            if (y >= y0 && y < y1)
                cnt += max(0, min(z, z1) - z0);
        }
        S += cnt;
    }
    return S;
}

// Deterministic re-pack of ev into INCOMING plane-major layout:
//   wIn[k*N + j] = weight of edge (j+DL[k] -> j)   (0 if that edge invalid).
// ev reads staged through LDS (coalesced segment load). Also zeroes ctr.
__global__ __launch_bounds__(256) void pack_w_kernel(
    const float* __restrict__ ev, float* __restrict__ w,
    unsigned* __restrict__ ctr) {
    __shared__ float lds[6144];
    int tid = threadIdx.x;
    int j = blockIdx.x * 256 + tid;
    if (blockIdx.x == 0) ctr[tid] = 0;   // 256 progress counters
    int z = j & 63, y = (j >> 6) & 63, x = j >> 12;

    int j0 = blockIdx.x * 256, j1 = j0 + 256;
    int Sblk = edge_prefix(j0 >> 12, (j0 >> 6) & 63, 0);
    int Send = edge_prefix(j1 >> 12, (j1 >> 6) & 63, 0);
    int Sj   = edge_prefix(x, y, z);

    int len = Send - Sblk;
    for (int i = tid; i < len; i += 256)
        lds[i] = ev[Sblk + i];
    __syncthreads();

    int rel = Sj - Sblk;
#pragma unroll
    for (int k = 0; k < KOFF; k++) {
        int nx = x + DXc[k], ny = y + DYc[k], nz = z + DZc[k];
        bool ok = ((unsigned)nx < 64u) & ((unsigned)ny < 64u) &
                  ((unsigned)nz < 64u);
        if (ok) {
            w[(23 - k) * N_TOTAL + (j + DLc[k])] = lds[rel];
            rel++;
        } else {
            w[k * N_TOTAL + j] = 0.0f;
        }
    }
}

// ------------------ persistent cooperative path ------------------
// One thread per neuron, all T steps; w/v/out-history in VGPRs.
// Sync protocol: bit-identical to validated rounds 10/11 (vmcnt drain ->
// per-slot atomicAdd publish -> relaxed sc1 observe of all 256 slots ->
// __syncthreads). Changes this round (data path only):
//  * multiplicative masking: p = praw * vmask[k]; the invalid-slot w select
//    is dropped (w=0 & p=0 => clip(0 - 0.005*o2) == 0 exactly since o2>=0).
//  * dy-only gather groups served from a double-buffered LDS copy of the
//    block's own out values (block = 16 y-rows; 14-16/16 waves in-block);
//    boundary waves fall back to the sc1 load. Same float values either way.
__global__ __launch_bounds__(1024, 1) void sim_kernel(
    const float* __restrict__ xext,
    const float* __restrict__ wpk,
    float* __restrict__ pb0,
    float* __restrict__ pb1,
    float* __restrict__ spk,
    unsigned* __restrict__ ctr,      // one counter per block (256)
    int T) {
#pragma clang fp contract(off)
    __shared__ float sout[2][1024];
    int tid = threadIdx.x;
    int j = blockIdx.x * 1024 + tid;
    int z = j & 63, y = (j >> 6) & 63, x = j >> 12;
    int lane = tid & 63;       // == z
    int lrow = tid >> 6;       // local y-row within block [0,16)

    float vmask[KOFF];
#pragma unroll
    for (int k = 0; k < KOFF; k++) {
        int nx = x + DXc[k], ny = y + DYc[k], nz = z + DZc[k];
        bool ok = ((unsigned)nx < 64u) & ((unsigned)ny < 64u) &
                  ((unsigned)nz < 64u);
        vmask[k] = ok ? 1.0f : 0.0f;
    }

    float w[KOFF];
#pragma unroll
    for (int k = 0; k < KOFF; k++) w[k] = wpk[k * N_TOTAL + j];

    const float decay = expf(-1.0f / 20.0f);
    float vmem = -65.0f;
    float o1 = 0.0f;   // out_{t-1}[j]
    float o2 = 0.0f;   // out_{t-2}[j]
    float xv = __builtin_nontemporal_load(xext + j);   // slice t=0

    for (int t = 0; t < T; t++) {
        float* pb = (t & 1) ? pb0 : pb1;   // buf[(t-1)&1]
        float* pw = (t & 1) ? pb1 : pb0;   // buf[t&1]
        const float* sr = sout[1 - (t & 1)];   // LDS out_{t-1}
        float* sw = sout[t & 1];               // LDS out_t

        // ---- wait: ALL blocks published step t (completed t-1) ----
        if (t >= 1) {
            if (tid < 64) {
                const unsigned* cp = ctr + tid * 4;
                for (;;) {
                    unsigned a = __hip_atomic_load(cp + 0, __ATOMIC_RELAXED,
                                                   __HIP_MEMORY_SCOPE_AGENT);
                    unsigned b = __hip_atomic_load(cp + 1, __ATOMIC_RELAXED,
                                                   __HIP_MEMORY_SCOPE_AGENT);
                    unsigned c = __hip_atomic_load(cp + 2, __ATOMIC_RELAXED,
                                                   __HIP_MEMORY_SCOPE_AGENT);
                    unsigned d = __hip_atomic_load(cp + 3, __ATOMIC_RELAXED,
                                                   __HIP_MEMORY_SCOPE_AGENT);
                    unsigned m = min(min(a, b), min(c, d));
                    if (m >= (unsigned)t) break;
                    __builtin_amdgcn_s_sleep(1);
                }
            }
            __syncthreads();
        }

        float syn = 0.0f;
        if (t >= 1) {
            // group gathers: validity / in-blockness wave-uniform -> scalar
            // branches. dy-only groups mostly from LDS, dx groups from L3.
            float r[NGRP];
#pragma unroll
            for (int g = 0; g < NGRP; g++) {
                int dxg = GDXc[g], dyg = GDYc[g];
                float rv = 0.0f;
                if (dxg == 0) {
                    int ly = lrow + dyg;
                    if ((unsigned)ly < 16u) {
                        rv = sr[tid + dyg * 64];        // ds_read, same value
                    } else {
                        int ny = y + dyg;
                        if ((unsigned)ny < 64u)
                            rv = __hip_atomic_load(pb + j + GDLc[g],
                                                   __ATOMIC_RELAXED,
                                                   __HIP_MEMORY_SCOPE_AGENT);
                    }
                } else {
                    int nx = x + dxg, ny = y + dyg;
                    if (((unsigned)nx < 64u) & ((unsigned)ny < 64u))
                        rv = __hip_atomic_load(pb + j + GDLc[g],
                                               __ATOMIC_RELAXED,
                                               __HIP_MEMORY_SCOPE_AGENT);
                }
                r[g] = rv;
            }
            if (t >= 2) {
                float h1 = 0.01f * o2;
                float h2 = 0.005f * o2;
#pragma unroll
                for (int k = 0; k < KOFF; k++) {
                    int g = GIDc[k], dz = DZc[k];
                    float src = (g < 0) ? o1 : r[g];
                    float praw = (dz == 0) ? src : __shfl(src, lane + dz, 64);
                    float p = praw * vmask[k];
                    float a = h1 * p;                 // == (0.01f*o2)*p
                    float b = h2 * (1.0f - p);        // == (0.005f*o2)*(1-p)
                    float c = 1e-5f * w[k];
                    float dw = (a - b) - c;
                    w[k] = fminf(fmaxf(w[k] + dw, 0.0f), 1.0f);
                    float m = w[k] * p;   // contract(off): mul then add
                    syn = syn + m;        // k-ascending == segment_sum order
                }
            } else {   // t == 1: syn with stored w, no plasticity yet
#pragma unroll
                for (int k = 0; k < KOFF; k++) {
                    int g = GIDc[k], dz = DZc[k];
                    float src = (g < 0) ? o1 : r[g];
                    float praw = (dz == 0) ? src : __shfl(src, lane + dz, 64);
                    float p = praw * vmask[k];
                    float m = w[k] * p;
                    syn = syn + m;
                }
            }
        }
        // t == 0: prev == 0 -> syn stays 0, no buffer read (poisoned ws ok).

        float I = syn + xv;
        float vn = (vmem * decay) + (I * (1.0f - decay));
        float spike = (vn >= -50.0f) ? 1.0f : 0.0f;
        float inhib = (vn <= -70.0f) ? 1.0f : 0.0f;
        float sg = 1.0f / (1.0f + expf(-((vn - (-60.0f)) * 0.5f)));
        float o = spike + ((1.0f - spike) * (1.0f - inhib)) * sg;
        vmem = (vn * (1.0f - spike)) + (spike * (-65.0f));
        __hip_atomic_store(pw + j, o, __ATOMIC_RELAXED,
                           __HIP_MEMORY_SCOPE_AGENT);
        sw[tid] = o;   // LDS copy (write buffer != read buffer: no WAR race)
        o2 = o1;
        o1 = o;

        // ---- publish: drain data store, then bump own slot (parallel RMW) ----
        __syncthreads();   // vmcnt(0)+lgkmcnt drain: pw & LDS visible
        if (tid == 0)
            __hip_atomic_fetch_add(ctr + blockIdx.x, 1u, __ATOMIC_RELAXED,
                                   __HIP_MEMORY_SCOPE_AGENT);

        // ---- post-publish streaming (latency hides under next wait) ----
        __builtin_nontemporal_store(spike, spk + (size_t)t * N_TOTAL + j);
        int tn = (t + 1 < T) ? (t + 1) : t;
        xv = __builtin_nontemporal_load(xext + (size_t)tn * N_TOTAL + j);
    }
}

// ------------------ per-step fallback path (validated round-3) ------------------
template <int MODE>
__global__ __launch_bounds__(256) void step_kernel(
    const float* __restrict__ xext,
    const float* __restrict__ w_old,
    float* __restrict__ w_new,
    const float* __restrict__ prev,
    const float* __restrict__ prev2,
    float* __restrict__ out,
    float* __restrict__ v,
    float* __restrict__ spk) {
#pragma clang fp contract(off)
    int j0 = (blockIdx.x * 256 + threadIdx.x) * 4;
    int z0 = j0 & 63, y = (j0 >> 6) & 63, x = j0 >> 12;

    float syn[4] = {0.0f, 0.0f, 0.0f, 0.0f};
    float pre2[4];
    if (MODE == 2) {
        f4 q = *(const f4*)(prev2 + j0);
        pre2[0] = q.x; pre2[1] = q.y; pre2[2] = q.z; pre2[3] = q.w;
    }

    if (MODE >= 1) {
#pragma unroll
        for (int k = 0; k < KOFF; k++) {
            int nx = x + DXc[k], nyy = y + DYc[k];
            bool okxy = ((unsigned)nx < 64u) & ((unsigned)nyy < 64u);
            int nzb = z0 + DZc[k];
            f4 wq = *(const f4*)(w_old + k * N_TOTAL + j0);
            float wv[4] = {wq.x, wq.y, wq.z, wq.w};
            float nw[4];
#pragma unroll
            for (int i = 0; i < 4; i++) {
                bool ok = okxy & ((unsigned)(nzb + i) < 64u);
                float p = ok ? prev[j0 + i + DLc[k]] : 0.0f;
                float nwi;
                if (MODE == 2) {
                    float a = (0.01f * pre2[i]) * p;
                    float b = (0.005f * pre2[i]) * (1.0f - p);
                    float c = 1e-5f * wv[i];
                    float dw = (a - b) - c;
                    float cl = fminf(fmaxf(wv[i] + dw, 0.0f), 1.0f);
                    nwi = ok ? cl : 0.0f;
                } else {
                    nwi = wv[i];
                }
                nw[i] = nwi;
                float m = nwi * p;
                syn[i] = syn[i] + m;
            }
            if (MODE == 2) {
                f4 s; s.x = nw[0]; s.y = nw[1]; s.z = nw[2]; s.w = nw[3];
                *(f4*)(w_new + k * N_TOTAL + j0) = s;
            }
        }
    }

    const float decay = expf(-1.0f / 20.0f);
    f4 xq;
    xq.x = __builtin_nontemporal_load(xext + j0 + 0);
    xq.y = __builtin_nontemporal_load(xext + j0 + 1);
    xq.z = __builtin_nontemporal_load(xext + j0 + 2);
    xq.w = __builtin_nontemporal_load(xext + j0 + 3);
    f4 vq;
    if (MODE >= 1) vq = *(const f4*)(v + j0);

    f4 vo, oo, so;
    float xv[4] = {xq.x, xq.y, xq.z, xq.w};
    float vv[4] = {vq.x, vq.y, vq.z, vq.w};
    float vr[4], orr[4], sr[4];
#pragma unroll
    for (int i = 0; i < 4; i++) {
        float myv = (MODE == 0) ? -65.0f : vv[i];
        float I = syn[i] + xv[i];
        float vn = (myv * decay) + (I * (1.0f - decay));
        float spike = (vn >= -50.0f) ? 1.0f : 0.0f;
        float inhib = (vn <= -70.0f) ? 1.0f : 0.0f;
        float sg = 1.0f / (1.0f + expf(-((vn - (-60.0f)) * 0.5f)));
        float o = spike + ((1.0f - spike) * (1.0f - inhib)) * sg;
        vr[i] = (vn * (1.0f - spike)) + (spike * (-65.0f));
        orr[i] = o;
        sr[i] = spike;
    }
    vo.x = vr[0]; vo.y = vr[1]; vo.z = vr[2]; vo.w = vr[3];
    oo.x = orr[0]; oo.y = orr[1]; oo.z = orr[2]; oo.w = orr[3];
    so.x = sr[0]; so.y = sr[1]; so.z = sr[2]; so.w = sr[3];
    *(f4*)(v + j0) = vo;
    *(f4*)(out + j0) = oo;
    __builtin_nontemporal_store(so, (f4*)(spk + j0));
}

extern "C" void kernel_launch(void* const* d_in, const int* in_sizes, int n_in,
                              void* d_out, int out_size, void* d_ws, size_t ws_size,
                              hipStream_t stream) {
    const float* xext = (const float*)d_in[0];
    const float* ev   = (const float*)d_in[1];
    float* spk = (float*)d_out;

    int T = in_sizes[0] / N_TOTAL;   // 50

    // Workspace: W0 (24N) | W1 (24N) | P0 | P1 | P2 | v | ctr[256]  ≈ 54.5 MB.
    float* W0 = (float*)d_ws;
    float* W1 = W0 + (size_t)N_TOTAL * KOFF;
    float* P0 = W1 + (size_t)N_TOTAL * KOFF;
    float* P1 = P0 + N_TOTAL;
    float* P2 = P1 + N_TOTAL;
    float* vb = P2 + N_TOTAL;
    unsigned* ctr = (unsigned*)(vb + N_TOTAL);

    pack_w_kernel<<<N_TOTAL / 256, 256, 0, stream>>>(ev, W0, ctr);

    const float* wpk = W0;
    void* args[] = {(void*)&xext, (void*)&wpk, (void*)&P0, (void*)&P1,
                    (void*)&spk, (void*)&ctr, (void*)&T};
    hipError_t cerr = hipLaunchCooperativeKernel((const void*)sim_kernel,
                                                 dim3(N_TOTAL / 1024),
                                                 dim3(1024), args, 0, stream);
    if (cerr == hipSuccess) return;
    (void)hipGetLastError();  // clear the failed-launch error state

    // Fallback: validated per-step path.
    float* P[3] = {P0, P1, P2};
    const int NB = N_TOTAL / 4 / 256;
    for (int t = 0; t < T; t++) {
        float* po  = P[t % 3];
        float* pr  = P[(t + 2) % 3];
        float* pr2 = P[(t + 1) % 3];
        const float* xt = xext + (size_t)t * N_TOTAL;
        float* st = spk + (size_t)t * N_TOTAL;
        if (t == 0) {
            step_kernel<0><<<NB, 256, 0, stream>>>(xt, W0, W1, pr, pr2, po, vb, st);
        } else if (t == 1) {
            step_kernel<1><<<NB, 256, 0, stream>>>(xt, W0, W1, pr, pr2, po, vb, st);
        } else {
            float* wo = (t & 1) ? W0 : W1;
            float* wn = (t & 1) ? W1 : W0;
            step_kernel<2><<<NB, 256, 0, stream>>>(xt, wo, wn, pr, pr2, po, vb, st);
        }
    }
}

// Round 13
// 403.719 us; speedup vs baseline: 14.1171x; 1.2767x over previous
//
#include <hip/hip_runtime.h>

#define GN 64
#define N_TOTAL (GN * GN * GN)   // 262144
#define KOFF 24

typedef float f4 __attribute__((ext_vector_type(4)));

// 24 Manhattan-radius-2 offsets, sorted by linear delta (dx*4096 + dy*64 + dz)
// ascending. List is symmetric under negation: inv(k) = 23 - k.
__device__ constexpr int DLc[KOFF] = {
    -8192, -4160, -4097, -4096, -4095, -4032,
     -128,   -65,   -64,   -63,    -2,    -1,
        1,     2,    63,    64,    65,   128,
     4032,  4095,  4096,  4097,  4160,  8192};
__device__ constexpr int DXc[KOFF] = {
    -2, -1, -1, -1, -1, -1, 0, 0, 0, 0, 0, 0,
     0,  0,  0,  0,  0,  0, 1, 1, 1, 1, 1, 2};
__device__ constexpr int DYc[KOFF] = {
     0, -1,  0,  0,  0,  1, -2, -1, -1, -1, 0, 0,
     0,  0,  1,  1,  1,  2, -1,  0,  0,  0, 1, 0};
__device__ constexpr int DZc[KOFF] = {
     0,  0, -1,  0,  1,  0,  0, -1,  0,  1, -2, -1,
     1,  2, -1,  0,  1,  0,  0, -1,  0,  1,  0,  0};

// 12 distinct (dx,dy) != (0,0) groups; a wave = one z-row, so the dz variants
// of a group are lane-shifts of the group's dz=0 element.
#define NGRP 12
__device__ constexpr int GDXc[NGRP] = {-2, -1, -1, -1,  0,  0, 0, 0,  1, 1, 1, 2};
__device__ constexpr int GDYc[NGRP] = { 0, -1,  0,  1, -2, -1, 1, 2, -1, 0, 1, 0};
__device__ constexpr int GDLc[NGRP] = {-8192, -4160, -4096, -4032, -128, -64,
                                        64, 128, 4032, 4096, 4160, 8192};
// group id per k (-1 = pure-z group, served from own o1)
__device__ constexpr int GIDc[KOFF] = {
    0, 1, 2, 2, 2, 3, 4, 5, 5, 5, -1, -1,
    -1, -1, 6, 6, 6, 7, 8, 9, 9, 9, 10, 11};

// Closed-form edge-count prefix: number of edges whose row-linear-index < j,
// evaluated at unraveled coords (x,y,z) of j.  Works for j == N via (64,0,0).
__device__ __forceinline__ int edge_prefix(int x, int y, int z) {
    int S = 0;
#pragma unroll
    for (int k = 0; k < KOFF; k++) {
        int dx = DXc[k], dy = DYc[k], dz = DZc[k];
        int x0 = max(0, -dx), x1 = min(64, 64 - dx);
        int y0 = max(0, -dy), y1 = min(64, 64 - dy);
        int z0 = max(0, -dz), z1 = min(64, 64 - dz);
        int ny = y1 - y0, nz = z1 - z0;
        int nxb = max(0, min(x, x1) - x0);
        int cnt = nxb * ny * nz;
        if (x >= x0 && x < x1) {
            cnt += max(0, min(y, y1) - y0) * nz;
            if (y >= y0 && y < y1)
                cnt += max(0, min(z, z1) - z0);
        }
        S += cnt;
    }
    return S;
}

// Deterministic re-pack of ev into INCOMING plane-major layout:
//   wIn[k*N + j] = weight of edge (j+DL[k] -> j)   (0 if that edge invalid).
// ev reads staged through LDS (coalesced segment load). Also zeroes ctr.
__global__ __launch_bounds__(256) void pack_w_kernel(
    const float* __restrict__ ev, float* __restrict__ w,
    unsigned* __restrict__ ctr) {
    __shared__ float lds[6144];
    int tid = threadIdx.x;
    int j = blockIdx.x * 256 + tid;
    if (blockIdx.x == 0) ctr[tid] = 0;   // 256 progress counters
    int z = j & 63, y = (j >> 6) & 63, x = j >> 12;

    int j0 = blockIdx.x * 256, j1 = j0 + 256;
    int Sblk = edge_prefix(j0 >> 12, (j0 >> 6) & 63, 0);
    int Send = edge_prefix(j1 >> 12, (j1 >> 6) & 63, 0);
    int Sj   = edge_prefix(x, y, z);

    int len = Send - Sblk;
    for (int i = tid; i < len; i += 256)
        lds[i] = ev[Sblk + i];
    __syncthreads();

    int rel = Sj - Sblk;
#pragma unroll
    for (int k = 0; k < KOFF; k++) {
        int nx = x + DXc[k], ny = y + DYc[k], nz = z + DZc[k];
        bool ok = ((unsigned)nx < 64u) & ((unsigned)ny < 64u) &
                  ((unsigned)nz < 64u);
        if (ok) {
            w[(23 - k) * N_TOTAL + (j + DLc[k])] = lds[rel];
            rel++;
        } else {
            w[k * N_TOTAL + j] = 0.0f;
        }
    }
}

// ------------------ persistent cooperative path ------------------
// One thread per neuron, all T steps; w/v/out-history in VGPRs.
// NEIGHBORHOOD SYNC with the VALIDATED publish: block B only depends on
// blocks B-8..B+8 (dx=+-2 -> +-8192 j -> +-8 blocks).  Publish is the
// R8/R10/R11/R12-validated sequence (vmcnt drain -> atomicAdd RMW to own
// slot); wait polls the 17 neighbor slots with relaxed sc1 loads (R10's
// validated poll pattern).  ctr[B'] >= t  <=>  B' completed step t-1
// including all of its reads, so the out ping-pong WAR is safe by symmetry
// of the dependency window; deadlock-free by induction on (block, step).
// R9's failure used a plain atomic-store publish - the one element changed.
__global__ __launch_bounds__(1024, 1) void sim_kernel(
    const float* __restrict__ xext,
    const float* __restrict__ wpk,
    float* __restrict__ pb0,
    float* __restrict__ pb1,
    float* __restrict__ spk,
    unsigned* __restrict__ ctr,      // one counter per block (256)
    int T) {
#pragma clang fp contract(off)
    __shared__ float sout[2][1024];
    int tid = threadIdx.x;
    int j = blockIdx.x * 1024 + tid;
    int z = j & 63, y = (j >> 6) & 63, x = j >> 12;
    int lane = tid & 63;       // == z
    int lrow = tid >> 6;       // local y-row within block [0,16)

    int bid = (int)blockIdx.x;
    int lo = max(0, bid - 8), hi = min((int)gridDim.x - 1, bid + 8);
    int ndep = hi - lo + 1;    // <= 17

    float vmask[KOFF];
#pragma unroll
    for (int k = 0; k < KOFF; k++) {
        int nx = x + DXc[k], ny = y + DYc[k], nz = z + DZc[k];
        bool ok = ((unsigned)nx < 64u) & ((unsigned)ny < 64u) &
                  ((unsigned)nz < 64u);
        vmask[k] = ok ? 1.0f : 0.0f;
    }

    float w[KOFF];
#pragma unroll
    for (int k = 0; k < KOFF; k++) w[k] = wpk[k * N_TOTAL + j];

    const float decay = expf(-1.0f / 20.0f);
    float vmem = -65.0f;
    float o1 = 0.0f;   // out_{t-1}[j]
    float o2 = 0.0f;   // out_{t-2}[j]
    float xv = __builtin_nontemporal_load(xext + j);   // slice t=0

    for (int t = 0; t < T; t++) {
        float* pb = (t & 1) ? pb0 : pb1;   // buf[(t-1)&1]
        float* pw = (t & 1) ? pb1 : pb0;   // buf[t&1]
        const float* sr = sout[1 - (t & 1)];   // LDS out_{t-1}
        float* sw = sout[t & 1];               // LDS out_t

        // ---- wait: neighborhood B-8..B+8 completed step t-1 ----
        if (t >= 1) {
            if (tid < ndep) {
                const unsigned* cp = ctr + lo + tid;
                while (__hip_atomic_load(cp, __ATOMIC_RELAXED,
                                         __HIP_MEMORY_SCOPE_AGENT) <
                       (unsigned)t)
                    __builtin_amdgcn_s_sleep(1);
            }
            __syncthreads();
        }

        float syn = 0.0f;
        if (t >= 1) {
            // group gathers: validity / in-blockness wave-uniform -> scalar
            // branches. dy-only groups mostly from LDS, dx groups from L3.
            float r[NGRP];
#pragma unroll
            for (int g = 0; g < NGRP; g++) {
                int dxg = GDXc[g], dyg = GDYc[g];
                float rv = 0.0f;
                if (dxg == 0) {
                    int ly = lrow + dyg;
                    if ((unsigned)ly < 16u) {
                        rv = sr[tid + dyg * 64];        // ds_read, same value
                    } else {
                        int ny = y + dyg;
                        if ((unsigned)ny < 64u)
                            rv = __hip_atomic_load(pb + j + GDLc[g],
                                                   __ATOMIC_RELAXED,
                                                   __HIP_MEMORY_SCOPE_AGENT);
                    }
                } else {
                    int nx = x + dxg, ny = y + dyg;
                    if (((unsigned)nx < 64u) & ((unsigned)ny < 64u))
                        rv = __hip_atomic_load(pb + j + GDLc[g],
                                               __ATOMIC_RELAXED,
                                               __HIP_MEMORY_SCOPE_AGENT);
                }
                r[g] = rv;
            }
            if (t >= 2) {
                float h1 = 0.01f * o2;
                float h2 = 0.005f * o2;
#pragma unroll
                for (int k = 0; k < KOFF; k++) {
                    int g = GIDc[k], dz = DZc[k];
                    float src = (g < 0) ? o1 : r[g];
                    float praw = (dz == 0) ? src : __shfl(src, lane + dz, 64);
                    float p = praw * vmask[k];
                    float a = h1 * p;                 // == (0.01f*o2)*p
                    float b = h2 * (1.0f - p);        // == (0.005f*o2)*(1-p)
                    float c = 1e-5f * w[k];
                    float dw = (a - b) - c;
                    w[k] = fminf(fmaxf(w[k] + dw, 0.0f), 1.0f);
                    float m = w[k] * p;   // contract(off): mul then add
                    syn = syn + m;        // k-ascending == segment_sum order
                }
            } else {   // t == 1: syn with stored w, no plasticity yet
#pragma unroll
                for (int k = 0; k < KOFF; k++) {
                    int g = GIDc[k], dz = DZc[k];
                    float src = (g < 0) ? o1 : r[g];
                    float praw = (dz == 0) ? src : __shfl(src, lane + dz, 64);
                    float p = praw * vmask[k];
                    float m = w[k] * p;
                    syn = syn + m;
                }
            }
        }
        // t == 0: prev == 0 -> syn stays 0, no buffer read (poisoned ws ok).

        float I = syn + xv;
        float vn = (vmem * decay) + (I * (1.0f - decay));
        float spike = (vn >= -50.0f) ? 1.0f : 0.0f;
        float inhib = (vn <= -70.0f) ? 1.0f : 0.0f;
        float sg = 1.0f / (1.0f + expf(-((vn - (-60.0f)) * 0.5f)));
        float o = spike + ((1.0f - spike) * (1.0f - inhib)) * sg;
        vmem = (vn * (1.0f - spike)) + (spike * (-65.0f));
        __hip_atomic_store(pw + j, o, __ATOMIC_RELAXED,
                           __HIP_MEMORY_SCOPE_AGENT);
        sw[tid] = o;   // LDS copy (write buffer != read buffer: no WAR race)
        o2 = o1;
        o1 = o;

        // ---- publish: drain data store, then bump own slot (RMW) ----
        __syncthreads();   // vmcnt(0)+lgkmcnt drain: pw & LDS visible
        if (tid == 0)
            __hip_atomic_fetch_add(ctr + bid, 1u, __ATOMIC_RELAXED,
                                   __HIP_MEMORY_SCOPE_AGENT);

        // ---- post-publish streaming (latency hides under next wait) ----
        __builtin_nontemporal_store(spike, spk + (size_t)t * N_TOTAL + j);
        int tn = (t + 1 < T) ? (t + 1) : t;
        xv = __builtin_nontemporal_load(xext + (size_t)tn * N_TOTAL + j);
    }
}

// ------------------ per-step fallback path (validated round-3) ------------------
template <int MODE>
__global__ __launch_bounds__(256) void step_kernel(
    const float* __restrict__ xext,
    const float* __restrict__ w_old,
    float* __restrict__ w_new,
    const float* __restrict__ prev,
    const float* __restrict__ prev2,
    float* __restrict__ out,
    float* __restrict__ v,
    float* __restrict__ spk) {
#pragma clang fp contract(off)
    int j0 = (blockIdx.x * 256 + threadIdx.x) * 4;
    int z0 = j0 & 63, y = (j0 >> 6) & 63, x = j0 >> 12;

    float syn[4] = {0.0f, 0.0f, 0.0f, 0.0f};
    float pre2[4];
    if (MODE == 2) {
        f4 q = *(const f4*)(prev2 + j0);
        pre2[0] = q.x; pre2[1] = q.y; pre2[2] = q.z; pre2[3] = q.w;
    }

    if (MODE >= 1) {
#pragma unroll
        for (int k = 0; k < KOFF; k++) {
            int nx = x + DXc[k], nyy = y + DYc[k];
            bool okxy = ((unsigned)nx < 64u) & ((unsigned)nyy < 64u);
            int nzb = z0 + DZc[k];
            f4 wq = *(const f4*)(w_old + k * N_TOTAL + j0);
            float wv[4] = {wq.x, wq.y, wq.z, wq.w};
            float nw[4];
#pragma unroll
            for (int i = 0; i < 4; i++) {
                bool ok = okxy & ((unsigned)(nzb + i) < 64u);
                float p = ok ? prev[j0 + i + DLc[k]] : 0.0f;
                float nwi;
                if (MODE == 2) {
                    float a = (0.01f * pre2[i]) * p;
                    float b = (0.005f * pre2[i]) * (1.0f - p);
                    float c = 1e-5f * wv[i];
                    float dw = (a - b) - c;
                    float cl = fminf(fmaxf(wv[i] + dw, 0.0f), 1.0f);
                    nwi = ok ? cl : 0.0f;
                } else {
                    nwi = wv[i];
                }
                nw[i] = nwi;
                float m = nwi * p;
                syn[i] = syn[i] + m;
            }
            if (MODE == 2) {
                f4 s; s.x = nw[0]; s.y = nw[1]; s.z = nw[2]; s.w = nw[3];
                *(f4*)(w_new + k * N_TOTAL + j0) = s;
            }
        }
    }

    const float decay = expf(-1.0f / 20.0f);
    f4 xq;
    xq.x = __builtin_nontemporal_load(xext + j0 + 0);
    xq.y = __builtin_nontemporal_load(xext + j0 + 1);
    xq.z = __builtin_nontemporal_load(xext + j0 + 2);
    xq.w = __builtin_nontemporal_load(xext + j0 + 3);
    f4 vq;
    if (MODE >= 1) vq = *(const f4*)(v + j0);

    f4 vo, oo, so;
    float xv[4] = {xq.x, xq.y, xq.z, xq.w};
    float vv[4] = {vq.x, vq.y, vq.z, vq.w};
    float vr[4], orr[4], sr[4];
#pragma unroll
    for (int i = 0; i < 4; i++) {
        float myv = (MODE == 0) ? -65.0f : vv[i];
        float I = syn[i] + xv[i];
        float vn = (myv * decay) + (I * (1.0f - decay));
        float spike = (vn >= -50.0f) ? 1.0f : 0.0f;
        float inhib = (vn <= -70.0f) ? 1.0f : 0.0f;
        float sg = 1.0f / (1.0f + expf(-((vn - (-60.0f)) * 0.5f)));
        float o = spike + ((1.0f - spike) * (1.0f - inhib)) * sg;
        vr[i] = (vn * (1.0f - spike)) + (spike * (-65.0f));
        orr[i] = o;
        sr[i] = spike;
    }
    vo.x = vr[0]; vo.y = vr[1]; vo.z = vr[2]; vo.w = vr[3];
    oo.x = orr[0]; oo.y = orr[1]; oo.z = orr[2]; oo.w = orr[3];
    so.x = sr[0]; so.y = sr[1]; so.z = sr[2]; so.w = sr[3];
    *(f4*)(v + j0) = vo;
    *(f4*)(out + j0) = oo;
    __builtin_nontemporal_store(so, (f4*)(spk + j0));
}

extern "C" void kernel_launch(void* const* d_in, const int* in_sizes, int n_in,
                              void* d_out, int out_size, void* d_ws, size_t ws_size,
                              hipStream_t stream) {
    const float* xext = (const float*)d_in[0];
    const float* ev   = (const float*)d_in[1];
    float* spk = (float*)d_out;

    int T = in_sizes[0] / N_TOTAL;   // 50

    // Workspace: W0 (24N) | W1 (24N) | P0 | P1 | P2 | v | ctr[256]  ≈ 54.5 MB.
    float* W0 = (float*)d_ws;
    float* W1 = W0 + (size_t)N_TOTAL * KOFF;
    float* P0 = W1 + (size_t)N_TOTAL * KOFF;
    float* P1 = P0 + N_TOTAL;
    float* P2 = P1 + N_TOTAL;
    float* vb = P2 + N_TOTAL;
    unsigned* ctr = (unsigned*)(vb + N_TOTAL);

    pack_w_kernel<<<N_TOTAL / 256, 256, 0, stream>>>(ev, W0, ctr);

    const float* wpk = W0;
    void* args[] = {(void*)&xext, (void*)&wpk, (void*)&P0, (void*)&P1,
                    (void*)&spk, (void*)&ctr, (void*)&T};
    hipError_t cerr = hipLaunchCooperativeKernel((const void*)sim_kernel,
                                                 dim3(N_TOTAL / 1024),
                                                 dim3(1024), args, 0, stream);
    if (cerr == hipSuccess) return;
    (void)hipGetLastError();  // clear the failed-launch error state

    // Fallback: validated per-step path.
    float* P[3] = {P0, P1, P2};
    const int NB = N_TOTAL / 4 / 256;
    for (int t = 0; t < T; t++) {
        float* po  = P[t % 3];
        float* pr  = P[(t + 2) % 3];
        float* pr2 = P[(t + 1) % 3];
        const float* xt = xext + (size_t)t * N_TOTAL;
        float* st = spk + (size_t)t * N_TOTAL;
        if (t == 0) {
            step_kernel<0><<<NB, 256, 0, stream>>>(xt, W0, W1, pr, pr2, po, vb, st);
        } else if (t == 1) {
            step_kernel<1><<<NB, 256, 0, stream>>>(xt, W0, W1, pr, pr2, po, vb, st);
        } else {
            float* wo = (t & 1) ? W0 : W1;
            float* wn = (t & 1) ? W1 : W0;
            step_kernel<2><<<NB, 256, 0, stream>>>(xt, wo, wn, pr, pr2, po, vb, st);
        }
    }
}